// Round 7
// baseline (245.208 us; speedup 1.0000x reference)
//
#include <hip/hip_runtime.h>
#include <hip/hip_bf16.h>
#include <math.h>

#define RESF 0.8f
#define LEAKYF 0.8f
#define BWSH 6
#define BWID 64
#define BSTRIDE 2432  // bucket capacity; lambda=2048, +8.5 sigma headroom
#define SPMMNB 2048   // persistent grid for pipelined spmm (8 blocks/CU)

typedef __attribute__((ext_vector_type(8))) short bs8;
typedef __attribute__((ext_vector_type(4))) float f32x4;

__device__ __forceinline__ void gload16(const void* g, void* l) {
  __builtin_amdgcn_global_load_lds((const __attribute__((address_space(1))) void*)g,
                                   (__attribute__((address_space(3))) void*)l, 16, 0, 0);
}

__device__ __forceinline__ float tanh_fast(float x) {
  float t = __expf(2.f * x);
  return 1.f - 2.f * __builtin_amdgcn_rcpf(1.f + t);
}
__device__ __forceinline__ float sigmoid_fast(float x) {
  return __builtin_amdgcn_rcpf(1.f + __expf(-x));
}
__device__ __forceinline__ ushort f2bf(float a) {
  __hip_bfloat16 h = __float2bfloat16(a);
  return *(ushort*)&h;
}

__device__ __forceinline__ void edge_full(int e,
    const int* __restrict__ rU, const int* __restrict__ cU, const float* __restrict__ vU,
    const int* __restrict__ rE, const int* __restrict__ cE, const float* __restrict__ vE,
    const int* __restrict__ rK, const int* __restrict__ cK, const float* __restrict__ vK,
    int EU, int EQ, int NU, int NQ, int& grow, int& gcol, float& val) {
  if (e < EU) { grow = rU[e]; gcol = cU[e]; val = vU[e]; return; }
  if ((e -= EU) < EQ) { grow = NU + rE[e]; gcol = NU + cE[e]; val = vE[e]; return; }
  e -= EQ;
  grow = NU + NQ + rK[e]; gcol = NU + NQ + cK[e]; val = vK[e];
}

// ---------------- setup: gcur[b] = 0 (counts), flags = 0 ----------------
__global__ __launch_bounds__(256) void k_setup(int* __restrict__ gcur, int* __restrict__ flags,
                                               int nbuck, int N_tot) {
  int i = blockIdx.x * 256 + threadIdx.x;
  if (i < nbuck) gcur[i] = 0;
  if (i < N_tot) flags[i] = 0;
}

// ---------------- bin: local bucket-sort per block, coalesced run writes (R1/R5-validated) ----------------
template <int BINR>
__global__ __launch_bounds__(1024) void k_bin(
    const int* __restrict__ rU, const int* __restrict__ cU, const float* __restrict__ vU,
    const int* __restrict__ rE, const int* __restrict__ cE, const float* __restrict__ vE,
    const int* __restrict__ rK, const int* __restrict__ cK, const float* __restrict__ vK,
    int* __restrict__ gcur, int2* __restrict__ tmp,
    int EU, int EQ, int EK, int NU, int NQ, int nbuck) {
  const int BINCH = BINR * 1024;
  extern __shared__ int l[];
  int metaN = (2 * nbuck + 3) & ~3;
  int* cnt = l;
  int* dstb = l + nbuck;
  int2* spk = (int2*)(l + metaN);
  ushort* sbk = (ushort*)(spk + BINCH);
  __shared__ int wsum[16];

  int t = threadIdx.x;
  int lane = t & 63, wid = t >> 6;
  for (int i = t; i < nbuck; i += 1024) cnt[i] = 0;
  __syncthreads();

  int E = EU + EQ + EK;
  int lo = blockIdx.x * BINCH;
  int hi = lo + BINCH < E ? lo + BINCH : E;
  int m = hi - lo;

  int2 pk[BINR];
  int bk[BINR];
#pragma unroll
  for (int k = 0; k < BINR; ++k) {
    int e = lo + t + k * 1024;
    bk[k] = -1;
    if (e < hi) {
      int grow, gcol;
      float val;
      edge_full(e, rU, cU, vU, rE, cE, vE, rK, cK, vK, EU, EQ, NU, NQ, grow, gcol, val);
      pk[k].x = ((grow & (BWID - 1)) << 26) | gcol;
      pk[k].y = __float_as_int(val);
      int b = grow >> BWSH;
      bk[k] = b;
      atomicAdd(&cnt[b], 1);
    }
  }
  __syncthreads();

  int carry = 0;
  for (int base = 0; base < nbuck; base += 1024) {
    int i = base + t;
    int x = (i < nbuck) ? cnt[i] : 0;
    int v = x;
#pragma unroll
    for (int d = 1; d < 64; d <<= 1) {
      int y = __shfl_up(v, d);
      if (lane >= d) v += y;
    }
    if (lane == 63) wsum[wid] = v;
    __syncthreads();
    if (t < 16) {
      int w = wsum[t];
#pragma unroll
      for (int d = 1; d < 16; d <<= 1) {
        int y = __shfl_up(w, d);
        if (t >= d) w += y;
      }
      wsum[t] = w;
    }
    __syncthreads();
    int excl = carry + ((wid > 0) ? wsum[wid - 1] : 0) + v - x;
    if (i < nbuck) {
      int gb = x ? atomicAdd(&gcur[i], x) : 0;
      dstb[i] = (i * BSTRIDE + gb) - excl;
      cnt[i] = excl;
    }
    carry += wsum[15];
    __syncthreads();
  }

#pragma unroll
  for (int k = 0; k < BINR; ++k) {
    if (bk[k] >= 0) {
      int p = atomicAdd(&cnt[bk[k]], 1);
      spk[p] = pk[k];
      sbk[p] = (ushort)bk[k];
    }
  }
  __syncthreads();

  for (int i = t; i < m; i += 1024) {
    int b = sbk[i];
    tmp[dstb[b] + i] = spk[i];
  }
}

// ---------------- sort pass: strided bucket segment -> row-sorted strided segment + roff2 ----------------
__global__ __launch_bounds__(256) void k_sort(const int2* __restrict__ tmp, int2* __restrict__ sorted,
                                              const int* __restrict__ gcur,
                                              int* __restrict__ roff2, int N_tot) {
  __shared__ int2 sedge[BSTRIDE];
  __shared__ int cnt[BWID];
  __shared__ int cur[BWID];
  int b = blockIdx.x, t = threadIdx.x;
  int beg = b * BSTRIDE;
  int cb = gcur[b];
  int m = cb < BSTRIDE ? cb : BSTRIDE;
  if (t < BWID) cnt[t] = 0;
  __syncthreads();
  for (int i = t; i < m; i += 256) {
    int2 pe = tmp[beg + i];
    sedge[i] = pe;
    atomicAdd(&cnt[((unsigned)pe.x) >> 26], 1);
  }
  __syncthreads();
  if (t < BWID) {
    int x = cnt[t];
    int v = x;
#pragma unroll
    for (int d = 1; d < 64; d <<= 1) {
      int y = __shfl_up(v, d);
      if (t >= d) v += y;
    }
    cur[t] = v - x;
    roff2[b * (BWID + 1) + t] = beg + v - x;
  } else if (t == BWID) {
    roff2[b * (BWID + 1) + BWID] = beg + m;
  }
  __syncthreads();
  for (int i = t; i < m; i += 256) {
    int2 pe = sedge[i];
    int rl = ((unsigned)pe.x) >> 26;
    int rank = atomicAdd(&cur[rl], 1);
    sorted[beg + rank] = pe;
  }
}

// ---------------- init lay0 (bf16) <- emb, fused with needed-row flag scatter ----------------
__global__ __launch_bounds__(256) void k_initflag(ushort* __restrict__ lay0,
                                                  const float* __restrict__ embU,
                                                  const float* __restrict__ embE,
                                                  const float* __restrict__ embK,
                                                  int n4U, int n4E, int n4K,
                                                  const int* __restrict__ user_id,
                                                  const int* __restrict__ question_id,
                                                  int* __restrict__ flags,
                                                  int B, int NU, int NUQ, int NC) {
  int gid = blockIdx.x * 256 + threadIdx.x;
  if (gid < B) {
    flags[user_id[gid]] = 1;
    flags[NU + question_id[gid]] = 1;
  }
  if (gid < NC) flags[NUQ + gid] = 1;

  int n4 = n4U + n4E + n4K;
  int stride = gridDim.x * 256;
  ushort4* c4 = (ushort4*)lay0;
  for (int i = gid; i < n4; i += stride) {
    const float4* src;
    int j = i;
    if (j < n4U) src = (const float4*)embU;
    else if ((j -= n4U) < n4E) src = (const float4*)embE;
    else { j -= n4E; src = (const float4*)embK; }
    float4 v = src[j];
    ushort4 u;
    u.x = f2bf(v.x); u.y = f2bf(v.y); u.z = f2bf(v.z); u.w = f2bf(v.w);
    c4[i] = u;
  }
}

// ---------------- SpMM inner window: 32 edges (8 srcs x 4 eh), 8 gathers in flight ----------------
__device__ __forceinline__ void spmm_window(const ushort* __restrict__ curb,
                                            int c, int vi, int m, int li, int eh,
                                            float& a0, float& a1, float& a2, float& a3) {
  for (int j = 0; j * 4 < m; j += 8) {
    int cc[8];
    float vf[8];
#pragma unroll
    for (int k = 0; k < 8; ++k) {
      int s = (j + k) * 4 + eh;
      cc[k] = __shfl(c, s);
      vf[k] = __int_as_float(__shfl(vi, s));
    }
    uint2 x[8];
#pragma unroll
    for (int k = 0; k < 8; ++k)
      x[k] = *(const uint2*)&curb[(size_t)cc[k] * 64 + 4 * li];
#pragma unroll
    for (int k = 0; k < 8; ++k) {
      a0 = fmaf(vf[k], __uint_as_float(x[k].x << 16), a0);
      a1 = fmaf(vf[k], __uint_as_float(x[k].x & 0xffff0000u), a1);
      a2 = fmaf(vf[k], __uint_as_float(x[k].y << 16), a2);
      a3 = fmaf(vf[k], __uint_as_float(x[k].y & 0xffff0000u), a3);
    }
  }
}

// row compute: first window from pre-loaded regs, further windows (rare) loaded inline
__device__ __forceinline__ void spmm_row(const ushort* __restrict__ curb,
                                         const int2* __restrict__ edges,
                                         int beg, int end, int c, int vi,
                                         int lane, int li, int eh,
                                         float& a0, float& a1, float& a2, float& a3) {
  int m0 = end - beg;
  m0 = m0 < 64 ? m0 : 64;
  spmm_window(curb, c, vi, m0, li, eh, a0, a1, a2, a3);
  for (int base = beg + 64; base < end; base += 64) {
    int rem = end - base;
    int m = rem < 64 ? rem : 64;
    int cc = 0, vv = 0;
    if (lane < m) {
      int2 pe = edges[base + lane];
      cc = pe.x & 0x3FFFFFF;
      vv = pe.y;
    }
    spmm_window(curb, cc, vv, m, li, eh, a0, a1, a2, a3);
  }
  a0 += __shfl_xor(a0, 16); a0 += __shfl_xor(a0, 32);
  a1 += __shfl_xor(a1, 16); a1 += __shfl_xor(a1, 32);
  a2 += __shfl_xor(a2, 16); a2 += __shfl_xor(a2, 32);
  a3 += __shfl_xor(a3, 16); a3 += __shfl_xor(a3, 32);
}

__device__ __forceinline__ int ro_of(int r) {
  return (r >> BWSH) * (BWID + 1) + (r & (BWID - 1));
}

// ---------------- pipelined CSR SpMM (persistent waves): nxt = A@cur + RES*cur ----------------
// 3-stage pipeline per wave: depth-2 roff2 prefetch, depth-1 edge-packet prefetch, compute.
// Hides the roff2->edges pointer-chase latency under the previous row's gather+FMA phase.
__global__ __launch_bounds__(256) void k_spmm2(const ushort* __restrict__ curb,
                                               ushort* __restrict__ nxtb,
                                               const int* __restrict__ roff2,
                                               const int2* __restrict__ edges, int n) {
  int nw = gridDim.x * 4;
  int wv = blockIdx.x * 4 + (threadIdx.x >> 6);
  int lane = threadIdx.x & 63;
  int li = lane & 15, eh = lane >> 4;

  int r = wv;
  if (r >= n) return;
  int ro = ro_of(r);
  int beg = roff2[ro], end = roff2[ro + 1];
  int r1 = r + nw, beg1 = 0, end1 = 0;
  if (r1 < n) {
    int ro1 = ro_of(r1);
    beg1 = roff2[ro1]; end1 = roff2[ro1 + 1];
  }
  int c = 0, vi = 0;
  {
    int m = end - beg; m = m < 64 ? m : 64;
    if (lane < m) { int2 pe = edges[beg + lane]; c = pe.x & 0x3FFFFFF; vi = pe.y; }
  }
  while (true) {
    // depth-2: roff2 for r+2*nw
    int r2 = r1 + nw, beg2 = 0, end2 = 0;
    if (r2 < n) {
      int ro2 = ro_of(r2);
      beg2 = roff2[ro2]; end2 = roff2[ro2 + 1];
    }
    // depth-1: edge packet for r1 (roff2 already resident from last iteration)
    int c1 = 0, vi1 = 0;
    if (r1 < n) {
      int m = end1 - beg1; m = m < 64 ? m : 64;
      if (lane < m) { int2 pe = edges[beg1 + lane]; c1 = pe.x & 0x3FFFFFF; vi1 = pe.y; }
    }
    // compute row r
    float a0 = 0.f, a1 = 0.f, a2 = 0.f, a3 = 0.f;
    spmm_row(curb, edges, beg, end, c, vi, lane, li, eh, a0, a1, a2, a3);
    if (eh == 0) {
      size_t gi = (size_t)r * 64 + 4 * li;
      uint2 cv = *(const uint2*)&curb[gi];
      a0 = fmaf(RESF, __uint_as_float(cv.x << 16), a0);
      a1 = fmaf(RESF, __uint_as_float(cv.x & 0xffff0000u), a1);
      a2 = fmaf(RESF, __uint_as_float(cv.y << 16), a2);
      a3 = fmaf(RESF, __uint_as_float(cv.y & 0xffff0000u), a3);
      uint2 o;
      o.x = ((unsigned)f2bf(a1) << 16) | f2bf(a0);
      o.y = ((unsigned)f2bf(a3) << 16) | f2bf(a2);
      *(uint2*)&nxtb[gi] = o;
    }
    if (r1 >= n) break;
    r = r1; beg = beg1; end = end1; c = c1; vi = vi1;
    r1 = r2; beg1 = beg2; end1 = end2;
  }
}

// ---------------- pipelined layer-3 SpMM, flags-gated, fused final accumulate ----------------
// flags prefetched at depth-2; edge packet only loaded for flagged rows.
__global__ __launch_bounds__(256) void k_spmm3(const ushort* __restrict__ curb,  // lay2
                                               const ushort* __restrict__ lay1,
                                               const float* __restrict__ embU,
                                               const float* __restrict__ embE,
                                               const float* __restrict__ embK,
                                               float* __restrict__ acc,
                                               const int* __restrict__ roff2,
                                               const int2* __restrict__ edges,
                                               const int* __restrict__ flags,
                                               int NU, int NQ, int n) {
  int nw = gridDim.x * 4;
  int wv = blockIdx.x * 4 + (threadIdx.x >> 6);
  int lane = threadIdx.x & 63;
  int li = lane & 15, eh = lane >> 4;

  int r = wv;
  if (r >= n) return;
  int fl = flags[r];
  int ro = ro_of(r);
  int beg = roff2[ro], end = roff2[ro + 1];
  int r1 = r + nw, fl1 = 0, beg1 = 0, end1 = 0;
  if (r1 < n) {
    fl1 = flags[r1];
    int ro1 = ro_of(r1);
    beg1 = roff2[ro1]; end1 = roff2[ro1 + 1];
  }
  int c = 0, vi = 0;
  if (fl) {
    int m = end - beg; m = m < 64 ? m : 64;
    if (lane < m) { int2 pe = edges[beg + lane]; c = pe.x & 0x3FFFFFF; vi = pe.y; }
  }
  while (true) {
    int r2 = r1 + nw, fl2 = 0, beg2 = 0, end2 = 0;
    if (r2 < n) {
      fl2 = flags[r2];
      int ro2 = ro_of(r2);
      beg2 = roff2[ro2]; end2 = roff2[ro2 + 1];
    }
    int c1 = 0, vi1 = 0;
    if (fl1) {
      int m = end1 - beg1; m = m < 64 ? m : 64;
      if (lane < m) { int2 pe = edges[beg1 + lane]; c1 = pe.x & 0x3FFFFFF; vi1 = pe.y; }
    }
    if (fl) {
      float a0 = 0.f, a1 = 0.f, a2 = 0.f, a3 = 0.f;
      spmm_row(curb, edges, beg, end, c, vi, lane, li, eh, a0, a1, a2, a3);
      if (eh == 0) {
        size_t gi = (size_t)r * 64 + 4 * li;
        const float* ep;
        if (r < NU) ep = embU + gi;
        else if (r < NU + NQ) ep = embE + (gi - (size_t)NU * 64);
        else ep = embK + (gi - (size_t)(NU + NQ) * 64);
        float4 e = *(const float4*)ep;
        uint2 l1 = *(const uint2*)&lay1[gi];
        uint2 c2 = *(const uint2*)&curb[gi];
        float c20 = __uint_as_float(c2.x << 16);
        float c21 = __uint_as_float(c2.x & 0xffff0000u);
        float c22 = __uint_as_float(c2.y << 16);
        float c23 = __uint_as_float(c2.y & 0xffff0000u);
        float4 o;
        o.x = e.x + __uint_as_float(l1.x << 16) + c20 + fmaf(RESF, c20, a0);
        o.y = e.y + __uint_as_float(l1.x & 0xffff0000u) + c21 + fmaf(RESF, c21, a1);
        o.z = e.z + __uint_as_float(l1.y << 16) + c22 + fmaf(RESF, c22, a2);
        o.w = e.w + __uint_as_float(l1.y & 0xffff0000u) + c23 + fmaf(RESF, c23, a3);
        *(float4*)&acc[gi] = o;
      }
    }
    if (r1 >= n) break;
    r = r1; fl = fl1; beg = beg1; end = end1; c = c1; vi = vi1;
    r1 = r2; fl1 = fl2; beg1 = beg2; end1 = end2;
  }
}

// ---------------- fused weight prep: kf + W1t/W2t/W3t transposes ----------------
__global__ __launch_bounds__(256) void k_prep(const float* __restrict__ acc_k,
                                              const float* __restrict__ W_k, const float* __restrict__ b_k,
                                              __hip_bfloat16* __restrict__ kfb,
                                              const float* __restrict__ M1_w, __hip_bfloat16* __restrict__ W1t,
                                              const float* __restrict__ M2_w, __hip_bfloat16* __restrict__ W2t,
                                              const float* __restrict__ M3_w, __hip_bfloat16* __restrict__ W3t) {
  int idx = blockIdx.x * 256 + threadIdx.x;
  if (idx < 65536) {
    int d = idx & 127, c = idx >> 7;
    float a = b_k[d];
#pragma unroll 8
    for (int k = 0; k < 64; ++k) a += 0.25f * acc_k[c * 64 + k] * W_k[k * 128 + d];
    float v = a > 0.f ? a : LEAKYF * a;
    kfb[c * 128 + d] = __float2bfloat16(v);
    return;
  }
  int j = idx - 65536;
  if (j < 262144) {  // M1: 512x512
    int n = j >> 9, k = j & 511;
    W1t[n * 512 + k] = __float2bfloat16(M1_w[k * 512 + n]);
    return;
  }
  j -= 262144;
  if (j < 131072) {  // M2: K=512, N=256
    int n = j >> 9, k = j & 511;
    W2t[n * 512 + k] = __float2bfloat16(M2_w[k * 256 + n]);
    return;
  }
  j -= 131072;
  if (j < 32768) {  // M3: K=256, N=128
    int n = j >> 8, k = j & 255;
    W3t[n * 256 + k] = __float2bfloat16(M3_w[k * 128 + n]);
  }
}

// ================= MLP phase =================
__global__ __launch_bounds__(256) void k_diff(
    const int* __restrict__ user_id, const int* __restrict__ question_id,
    const float* __restrict__ acc_u, const float* __restrict__ acc_e,
    const float* __restrict__ W_s, const float* __restrict__ b_s,
    const float* __restrict__ W_e, const float* __restrict__ b_e,
    const float* __restrict__ W_d, const float* __restrict__ b_d,
    __hip_bfloat16* __restrict__ diff, float* __restrict__ disc, int B) {
  __shared__ float bs_l[16 * 64];
  __shared__ float be_l[16 * 64];
  int t = threadIdx.x;
  int row0 = blockIdx.x * 16;
  for (int i = t; i < 16 * 64; i += 256) {
    int r = i >> 6, d = i & 63;
    int gb = row0 + r;
    bs_l[i] = 0.25f * acc_u[(size_t)user_id[gb] * 64 + d];
    be_l[i] = 0.25f * acc_e[(size_t)question_id[gb] * 64 + d];
  }
  __syncthreads();

  int j = t & 127, half = t >> 7;
  float as[8], ae[8];
#pragma unroll
  for (int rr = 0; rr < 8; ++rr) { as[rr] = b_s[j]; ae[rr] = b_e[j]; }
#pragma unroll 4
  for (int k = 0; k < 64; ++k) {
    float ws = W_s[k * 128 + j];
    float we = W_e[k * 128 + j];
#pragma unroll
    for (int rr = 0; rr < 8; ++rr) {
      as[rr] = fmaf(bs_l[(half * 8 + rr) * 64 + k], ws, as[rr]);
      ae[rr] = fmaf(be_l[(half * 8 + rr) * 64 + k], we, ae[rr]);
    }
  }
#pragma unroll
  for (int rr = 0; rr < 8; ++rr) {
    float sfv = as[rr] > 0.f ? as[rr] : LEAKYF * as[rr];
    float efv = ae[rr] > 0.f ? ae[rr] : LEAKYF * ae[rr];
    diff[(size_t)(row0 + half * 8 + rr) * 128 + j] = __float2bfloat16(sfv - efv);
  }
  if (t < 16) {
    float a = b_d[0];
#pragma unroll 8
    for (int k = 0; k < 64; ++k) a = fmaf(be_l[t * 64 + k], W_d[k], a);
    disc[row0 + t] = sigmoid_fast(a);
  }
}

// MODE 0: C = disc * (A@B^T) * q_table   (state)
// MODE 1: C = tanh(A@B^T + bias)
// MODE 2: fused tail: h3 = tanh(A@B^T + bias); out = sigmoid(h3 @ M4w + M4b)  (no C write)
template <int K, int MODE>
__global__ __launch_bounds__(256) void k_gemm(
    const __hip_bfloat16* __restrict__ A, const __hip_bfloat16* __restrict__ Bw,
    __hip_bfloat16* __restrict__ C, int N,
    const float* __restrict__ bias,
    const float* __restrict__ disc, const int* __restrict__ qid,
    const float* __restrict__ q_table,
    const float* __restrict__ M4w, const float* __restrict__ M4b,
    float* __restrict__ outp) {
  __shared__ __align__(16) short lA[128 * 32];
  __shared__ __align__(16) short lB[128 * 32];
  __shared__ float s_disc[128];
  __shared__ int s_qid[128];
  __shared__ float s_bias[128];
  __shared__ float sM4[128];
  __shared__ float spart[128][2];

  int t = threadIdx.x;
  int lane = t & 63;
  int w = t >> 6;
  int wr = (w >> 1) * 64, wc = (w & 1) * 64;
  int bm0 = blockIdx.y * 128, bn0 = blockIdx.x * 128;

  if (MODE == 0) {
    if (t < 128) {
      s_disc[t] = disc[bm0 + t];
      s_qid[t] = qid[bm0 + t];
    }
  } else {
    if (t < 128) s_bias[t] = bias[bn0 + t];
    if (MODE == 2 && t < 128) sM4[t] = M4w[t];
  }

  int off0 = t, off1 = 256 + t;
  int rA0 = off0 >> 2, gq0 = (off0 & 3) ^ ((rA0 >> 1) & 3);
  int rA1 = off1 >> 2, gq1 = (off1 & 3) ^ ((rA1 >> 1) & 3);

  const __hip_bfloat16* Ab = A + (size_t)bm0 * K;
  const __hip_bfloat16* Bb = Bw + (size_t)bn0 * K;

  f32x4 acc[4][4] = {};
  int q = lane >> 4, fr = lane & 15;

  for (int k0 = 0; k0 < K; k0 += 32) {
    __syncthreads();
    gload16(Ab + (size_t)rA0 * K + k0 + gq0 * 8, lA + (size_t)off0 * 8);
    gload16(Ab + (size_t)rA1 * K + k0 + gq1 * 8, lA + (size_t)off1 * 8);
    gload16(Bb + (size_t)rA0 * K + k0 + gq0 * 8, lB + (size_t)off0 * 8);
    gload16(Bb + (size_t)rA1 * K + k0 + gq1 * 8, lB + (size_t)off1 * 8);
    __syncthreads();

    bs8 af[4], bf[4];
#pragma unroll
    for (int mi = 0; mi < 4; ++mi) {
      int row = wr + mi * 16 + fr;
      int a16 = row * 4 + (q ^ ((row >> 1) & 3));
      af[mi] = *(const bs8*)&lA[a16 * 8];
    }
#pragma unroll
    for (int ni = 0; ni < 4; ++ni) {
      int col = wc + ni * 16 + fr;
      int b16 = col * 4 + (q ^ ((col >> 1) & 3));
      bf[ni] = *(const bs8*)&lB[b16 * 8];
    }
#pragma unroll
    for (int mi = 0; mi < 4; ++mi)
#pragma unroll
      for (int ni = 0; ni < 4; ++ni)
        acc[mi][ni] = __builtin_amdgcn_mfma_f32_16x16x32_bf16(af[mi], bf[ni], acc[mi][ni], 0, 0, 0);
  }

  if (MODE == 2) {
#pragma unroll
    for (int mi = 0; mi < 4; ++mi) {
#pragma unroll
      for (int j = 0; j < 4; ++j) {
        int lr = wr + mi * 16 + q * 4 + j;
        float p = 0.f;
#pragma unroll
        for (int ni = 0; ni < 4; ++ni) {
          int lc = wc + ni * 16 + fr;
          p += tanh_fast(acc[mi][ni][j] + s_bias[lc]) * sM4[lc];
        }
        p += __shfl_xor(p, 1);
        p += __shfl_xor(p, 2);
        p += __shfl_xor(p, 4);
        p += __shfl_xor(p, 8);
        if (fr == 0) spart[lr][w & 1] = p;
      }
    }
    __syncthreads();
    if (t < 128) outp[bm0 + t] = sigmoid_fast(spart[t][0] + spart[t][1] + M4b[0]);
    return;
  }

#pragma unroll
  for (int mi = 0; mi < 4; ++mi) {
    int lr0 = wr + mi * 16 + q * 4;
#pragma unroll
    for (int j = 0; j < 4; ++j) {
      int lr = lr0 + j;
      size_t gr = bm0 + lr;
      float dsc = 0.f;
      size_t qrow = 0;
      if (MODE == 0) {
        dsc = s_disc[lr];
        qrow = (size_t)s_qid[lr] * 512;
      }
#pragma unroll
      for (int ni = 0; ni < 4; ++ni) {
        int lc = wc + ni * 16 + fr;
        int gc = bn0 + lc;
        float v = acc[mi][ni][j];
        if (MODE == 0) {
          v = dsc * v * q_table[qrow + gc];
        } else {
          v = tanh_fast(v + s_bias[lc]);
        }
        C[gr * N + gc] = __float2bfloat16(v);
      }
    }
  }
}

// ---------------- host ----------------
static inline int iminh(int a, int b) { return a < b ? a : b; }
static inline size_t rnd4(size_t x) { return (x + 3) & ~(size_t)3; }

extern "C" void kernel_launch(void* const* d_in, const int* in_sizes, int n_in,
                              void* d_out, int out_size, void* d_ws, size_t ws_size,
                              hipStream_t stream) {
  const int* user_id = (const int*)d_in[0];
  const int* question_id = (const int*)d_in[1];
  const float* q_table = (const float*)d_in[2];
  const int* u_row = (const int*)d_in[3];
  const int* u_col = (const int*)d_in[4];
  const float* u_val = (const float*)d_in[5];
  const int* e_row = (const int*)d_in[6];
  const int* e_col = (const int*)d_in[7];
  const float* e_val = (const float*)d_in[8];
  const int* k_row = (const int*)d_in[9];
  const int* k_col = (const int*)d_in[10];
  const float* k_val = (const float*)d_in[11];
  const float* student_emb = (const float*)d_in[12];
  const float* exercise_emb = (const float*)d_in[13];
  const float* knowledge_emb = (const float*)d_in[14];
  const float* W_s = (const float*)d_in[15];
  const float* b_s = (const float*)d_in[16];
  const float* W_e = (const float*)d_in[17];
  const float* b_e = (const float*)d_in[18];
  const float* W_k = (const float*)d_in[19];
  const float* b_k = (const float*)d_in[20];
  const float* W_d = (const float*)d_in[21];
  const float* b_d = (const float*)d_in[22];
  const float* M1_w = (const float*)d_in[23];
  const float* M1_b = (const float*)d_in[24];
  const float* M2_w = (const float*)d_in[25];
  const float* M2_b = (const float*)d_in[26];
  const float* M3_w = (const float*)d_in[27];
  const float* M3_b = (const float*)d_in[28];
  const float* M4_w = (const float*)d_in[29];
  const float* M4_b = (const float*)d_in[30];

  int B = in_sizes[0];
  int NU = in_sizes[12] / 64;
  int NQ = in_sizes[13] / 64;
  int NC = in_sizes[14] / 64;
  int EU = in_sizes[3];
  int EQ = in_sizes[6];
  int EK = in_sizes[9];
  int N_tot = NU + NQ + NC;
  int E_tot = EU + EQ + EK;
  int nbuck = (N_tot + BWID - 1) >> BWSH;

  // ---- workspace: persistent acc + kfb, then UNION region ----
  float* w = (float*)d_ws;
  float* acc = w; w += rnd4((size_t)N_tot * 64);
  __hip_bfloat16* kfb = (__hip_bfloat16*)w; w += rnd4(512 * 128 / 2);
  float* U = w;

  float* acc_u = acc;
  float* acc_e = acc + (size_t)NU * 64;
  float* acc_k = acc + (size_t)(NU + NQ) * 64;

  // conv-phase layout within U
  float* cw = U;
  ushort* lay0 = (ushort*)cw; cw += rnd4((size_t)N_tot * 32);
  ushort* lay1 = (ushort*)cw; cw += rnd4((size_t)N_tot * 32);
  int2* sorted = (int2*)cw;   cw += rnd4((size_t)nbuck * BSTRIDE * 2);
  int* gcur = (int*)cw;  cw += rnd4(nbuck);
  int* flags = (int*)cw; cw += rnd4(N_tot);
  int* roff2 = (int*)cw; cw += rnd4((size_t)nbuck * (BWID + 1) + 4);
  // alias region: tmp (dead after k_sort) overlaps lay2
  float* alias0 = cw;
  int2* tmp = (int2*)alias0;
  ushort* lay2 = (ushort*)alias0;
  {
    size_t tmp_f = rnd4((size_t)nbuck * BSTRIDE * 2);
    size_t lay_f = rnd4((size_t)N_tot * 32);
    cw += (tmp_f > lay_f ? tmp_f : lay_f);
  }

  // mlp-phase layout within U (overlaps conv layout; conv artifacts dead by then)
  float* mw = U;
  __hip_bfloat16* W1t = (__hip_bfloat16*)mw; mw += rnd4(512 * 512 / 2);
  __hip_bfloat16* W2t = (__hip_bfloat16*)mw; mw += rnd4(256 * 512 / 2);
  __hip_bfloat16* W3t = (__hip_bfloat16*)mw; mw += rnd4(128 * 256 / 2);
  __hip_bfloat16* diff = (__hip_bfloat16*)mw; mw += rnd4((size_t)B * 128 / 2);
  float* disc = mw; mw += rnd4(B);
  __hip_bfloat16* state = (__hip_bfloat16*)mw; mw += rnd4((size_t)B * 512 / 2);
  __hip_bfloat16* h1 = (__hip_bfloat16*)mw;    mw += rnd4((size_t)B * 512 / 2);
  __hip_bfloat16* h2 = state;

  // ---- one-time opt-in for >64KB dynamic LDS on the big k_bin variant ----
  static int big_ok = -1;
  if (big_ok < 0) {
    hipError_t e = hipFuncSetAttribute((const void*)k_bin<10>,
                                       hipFuncAttributeMaxDynamicSharedMemorySize,
                                       160 * 1024);
    big_ok = (e == hipSuccess) ? 1 : 0;
    (void)hipGetLastError();  // clear any sticky error from a failed probe
  }

  // ---- setup + edge build: local bucket-sort bin -> row sort (strided, no scan) ----
  {
    int metaN = (2 * nbuck + 3) & ~3;
    k_setup<<<(N_tot + 255) / 256, 256, 0, stream>>>(gcur, flags, nbuck, N_tot);
    if (big_ok) {
      const int BINCH = 10240;
      int gsb = (E_tot + BINCH - 1) / BINCH;
      size_t ldsb = (size_t)metaN * 4 + (size_t)BINCH * 8 + (size_t)BINCH * 2;
      k_bin<10><<<gsb, 1024, ldsb, stream>>>(u_row, u_col, u_val, e_row, e_col, e_val,
                                             k_row, k_col, k_val, gcur, tmp,
                                             EU, EQ, EK, NU, NQ, nbuck);
    } else {
      const int BINCH = 5120;
      int gsb = (E_tot + BINCH - 1) / BINCH;
      size_t ldsb = (size_t)metaN * 4 + (size_t)BINCH * 8 + (size_t)BINCH * 2;
      k_bin<5><<<gsb, 1024, ldsb, stream>>>(u_row, u_col, u_val, e_row, e_col, e_val,
                                            k_row, k_col, k_val, gcur, tmp,
                                            EU, EQ, EK, NU, NQ, nbuck);
    }
    k_sort<<<nbuck, 256, 0, stream>>>(tmp, sorted, gcur, roff2, N_tot);
  }

  // ---- convolution: init+flags fused; layers 1-2 pipelined, layer 3 flags-pruned pipelined ----
  {
    int n4 = N_tot * 16;
    int gs = iminh((n4 + 255) / 256, 2048);
    k_initflag<<<gs, 256, 0, stream>>>(lay0, student_emb, exercise_emb, knowledge_emb,
                                       NU * 16, NQ * 16, NC * 16,
                                       user_id, question_id, flags, B, NU, NU + NQ, NC);
    k_spmm2<<<SPMMNB, 256, 0, stream>>>(lay0, lay1, roff2, sorted, N_tot);
    k_spmm2<<<SPMMNB, 256, 0, stream>>>(lay1, lay2, roff2, sorted, N_tot);
    k_spmm3<<<SPMMNB, 256, 0, stream>>>(lay2, lay1, student_emb, exercise_emb,
                                        knowledge_emb, acc, roff2, sorted,
                                        flags, NU, NQ, N_tot);
  }

  // ---- MLP phase (overwrites U; conv done) ----
  k_prep<<<(65536 + 262144 + 131072 + 32768) / 256, 256, 0, stream>>>(
      acc_k, W_k, b_k, kfb, M1_w, W1t, M2_w, W2t, M3_w, W3t);

  k_diff<<<B / 16, 256, 0, stream>>>(user_id, question_id, acc_u, acc_e,
                                     W_s, b_s, W_e, b_e, W_d, b_d, diff, disc, B);

  k_gemm<128, 0><<<dim3(512 / 128, B / 128), 256, 0, stream>>>(
      diff, kfb, state, 512, nullptr, disc, question_id, q_table, nullptr, nullptr, nullptr);
  k_gemm<512, 1><<<dim3(512 / 128, B / 128), 256, 0, stream>>>(
      state, W1t, h1, 512, M1_b, nullptr, nullptr, nullptr, nullptr, nullptr, nullptr);
  k_gemm<512, 1><<<dim3(256 / 128, B / 128), 256, 0, stream>>>(
      h1, W2t, h2, 256, M2_b, nullptr, nullptr, nullptr, nullptr, nullptr, nullptr);
  k_gemm<256, 2><<<dim3(1, B / 128), 256, 0, stream>>>(
      h2, W3t, nullptr, 128, M3_b, nullptr, nullptr, nullptr, M4_w, M4_b, (float*)d_out);
}

// Round 8
// 223.429 us; speedup vs baseline: 1.0975x; 1.0975x over previous
//
#include <hip/hip_runtime.h>
#include <hip/hip_bf16.h>
#include <math.h>

#define RESF 0.8f
#define LEAKYF 0.8f
#define BWSH 6
#define BWID 64
#define BSTRIDE 2432  // bucket capacity; lambda=2048, +8.5 sigma headroom

typedef __attribute__((ext_vector_type(8))) short bs8;
typedef __attribute__((ext_vector_type(4))) float f32x4;

__device__ __forceinline__ void gload16(const void* g, void* l) {
  __builtin_amdgcn_global_load_lds((const __attribute__((address_space(1))) void*)g,
                                   (__attribute__((address_space(3))) void*)l, 16, 0, 0);
}

__device__ __forceinline__ float tanh_fast(float x) {
  float t = __expf(2.f * x);
  return 1.f - 2.f * __builtin_amdgcn_rcpf(1.f + t);
}
__device__ __forceinline__ float sigmoid_fast(float x) {
  return __builtin_amdgcn_rcpf(1.f + __expf(-x));
}
__device__ __forceinline__ ushort f2bf(float a) {
  __hip_bfloat16 h = __float2bfloat16(a);
  return *(ushort*)&h;
}

__device__ __forceinline__ void edge_full(int e,
    const int* __restrict__ rU, const int* __restrict__ cU, const float* __restrict__ vU,
    const int* __restrict__ rE, const int* __restrict__ cE, const float* __restrict__ vE,
    const int* __restrict__ rK, const int* __restrict__ cK, const float* __restrict__ vK,
    int EU, int EQ, int NU, int NQ, int& grow, int& gcol, float& val) {
  if (e < EU) { grow = rU[e]; gcol = cU[e]; val = vU[e]; return; }
  if ((e -= EU) < EQ) { grow = NU + rE[e]; gcol = NU + cE[e]; val = vE[e]; return; }
  e -= EQ;
  grow = NU + NQ + rK[e]; gcol = NU + NQ + cK[e]; val = vK[e];
}

// ---------------- setup: gcur[b] = b*BSTRIDE, flags = 0 ----------------
__global__ __launch_bounds__(256) void k_setup(int* __restrict__ gcur, int* __restrict__ flags,
                                               int nbuck, int N_tot) {
  int i = blockIdx.x * 256 + threadIdx.x;
  if (i < nbuck) gcur[i] = i * BSTRIDE;
  if (i < N_tot) flags[i] = 0;
}

// ---------------- bin: local bucket-sort per block, coalesced run writes (R1-validated) ----------------
// BINR=edges/thread; BINCH=BINR*1024. BINR=10 needs 108.6KB dyn LDS (>64KB opt-in);
// BINR=5 (60.4KB) is the validated fallback.
template <int BINR>
__global__ __launch_bounds__(1024) void k_bin(
    const int* __restrict__ rU, const int* __restrict__ cU, const float* __restrict__ vU,
    const int* __restrict__ rE, const int* __restrict__ cE, const float* __restrict__ vE,
    const int* __restrict__ rK, const int* __restrict__ cK, const float* __restrict__ vK,
    int* __restrict__ gcur, int2* __restrict__ tmp,
    int EU, int EQ, int EK, int NU, int NQ, int nbuck) {
  const int BINCH = BINR * 1024;
  extern __shared__ int l[];
  int metaN = (2 * nbuck + 3) & ~3;
  int* cnt = l;                           // [nbuck] counts -> exclusive offsets -> cursors
  int* dstb = l + nbuck;                  // [nbuck] gbase - local exclusive offset
  int2* spk = (int2*)(l + metaN);         // [BINCH] staged packed edges
  ushort* sbk = (ushort*)(spk + BINCH);   // [BINCH] staged bucket ids
  __shared__ int wsum[16];

  int t = threadIdx.x;
  int lane = t & 63, wid = t >> 6;
  for (int i = t; i < nbuck; i += 1024) cnt[i] = 0;
  __syncthreads();

  int E = EU + EQ + EK;
  int lo = blockIdx.x * BINCH;
  int hi = lo + BINCH < E ? lo + BINCH : E;
  int m = hi - lo;  // edges staged by this block

  int2 pk[BINR];
  int bk[BINR];
#pragma unroll
  for (int k = 0; k < BINR; ++k) {
    int e = lo + t + k * 1024;
    bk[k] = -1;
    if (e < hi) {
      int grow, gcol;
      float val;
      edge_full(e, rU, cU, vU, rE, cE, vE, rK, cK, vK, EU, EQ, NU, NQ, grow, gcol, val);
      pk[k].x = ((grow & (BWID - 1)) << 26) | gcol;
      pk[k].y = __float_as_int(val);
      int b = grow >> BWSH;
      bk[k] = b;
      atomicAdd(&cnt[b], 1);
    }
  }
  __syncthreads();

  // block-wide exclusive scan over nbuck counts (with carry across 1024-wide windows);
  // simultaneously reserve global space and build dstb.
  int carry = 0;
  for (int base = 0; base < nbuck; base += 1024) {
    int i = base + t;
    int x = (i < nbuck) ? cnt[i] : 0;
    int v = x;
#pragma unroll
    for (int d = 1; d < 64; d <<= 1) {
      int y = __shfl_up(v, d);
      if (lane >= d) v += y;
    }
    if (lane == 63) wsum[wid] = v;
    __syncthreads();
    if (t < 16) {
      int w = wsum[t];
#pragma unroll
      for (int d = 1; d < 16; d <<= 1) {
        int y = __shfl_up(w, d);
        if (t >= d) w += y;
      }
      wsum[t] = w;
    }
    __syncthreads();
    int excl = carry + ((wid > 0) ? wsum[wid - 1] : 0) + v - x;
    if (i < nbuck) {
      int gb = x ? atomicAdd(&gcur[i], x) : 0;
      dstb[i] = gb - excl;
      cnt[i] = excl;  // cursor init for scatter phase
    }
    carry += wsum[15];
    __syncthreads();
  }

  // scatter into LDS staging in bucket-sorted order
#pragma unroll
  for (int k = 0; k < BINR; ++k) {
    if (bk[k] >= 0) {
      int p = atomicAdd(&cnt[bk[k]], 1);
      spk[p] = pk[k];
      sbk[p] = (ushort)bk[k];
    }
  }
  __syncthreads();

  // coalesced copy: runs of same-bucket elements land at consecutive global addresses
  for (int i = t; i < m; i += 1024) {
    int b = sbk[i];
    tmp[dstb[b] + i] = spk[i];
  }
}

// ---------------- compact-offset scan over bucket counts (cnt[b] = gcur[b]-b*BSTRIDE) ----------------
__global__ __launch_bounds__(1024) void k_scan2(const int* __restrict__ gcur, int* __restrict__ boff, int n) {
  __shared__ int s[16];
  int tid = threadIdx.x;
  int lane = tid & 63, wid = tid >> 6;
  int carry = 0;
  for (int base = 0; base < n; base += 1024) {
    int i = base + tid;
    int x = (i < n) ? (gcur[i] - i * BSTRIDE) : 0;
    int v = x;
#pragma unroll
    for (int d = 1; d < 64; d <<= 1) {
      int t = __shfl_up(v, d);
      if (lane >= d) v += t;
    }
    if (lane == 63) s[wid] = v;
    __syncthreads();
    if (tid < 16) {
      int w = s[tid];
#pragma unroll
      for (int d = 1; d < 16; d <<= 1) {
        int t = __shfl_up(w, d);
        if (tid >= d) w += t;
      }
      s[tid] = w;
    }
    __syncthreads();
    int wofs = (wid > 0) ? s[wid - 1] : 0;
    int total = s[15];
    if (i < n) boff[i] = carry + wofs + v - x;
    carry += total;
    __syncthreads();
  }
  if (tid == 0) boff[n] = carry;
}

// ---------------- sort pass: strided bucket segment -> compact exact CSR + row offsets ----------------
// LDS-staged: read the bucket segment from global ONCE (histogram pass), scatter from LDS.
__global__ __launch_bounds__(256) void k_sort(const int2* __restrict__ tmp, int2* __restrict__ sorted,
                                              const int* __restrict__ gcur, const int* __restrict__ boff,
                                              int* __restrict__ roff, int N_tot, int E_tot) {
  __shared__ int2 sedge[BSTRIDE];  // 19456 B
  __shared__ int cnt[BWID];
  __shared__ int cur[BWID];
  int b = blockIdx.x, t = threadIdx.x;
  int beg = b * BSTRIDE, end = gcur[b];
  int m = end - beg;
  if (m > BSTRIDE) m = BSTRIDE;
  int dst = boff[b];
  if (t < BWID) cnt[t] = 0;
  __syncthreads();
  for (int i = t; i < m; i += 256) {
    int2 pe = tmp[beg + i];
    sedge[i] = pe;
    atomicAdd(&cnt[((unsigned)pe.x) >> 26], 1);
  }
  __syncthreads();
  if (t < BWID) {
    int x = cnt[t];
    int v = x;
#pragma unroll
    for (int d = 1; d < 64; d <<= 1) {
      int y = __shfl_up(v, d);
      if (t >= d) v += y;
    }
    cur[t] = v - x;  // exclusive intra-bucket offset
    int r = (b << BWSH) + t;
    if (r < N_tot) roff[r] = dst + v - x;
  }
  __syncthreads();
  for (int i = t; i < m; i += 256) {
    int2 pe = sedge[i];
    int rl = ((unsigned)pe.x) >> 26;
    int rank = atomicAdd(&cur[rl], 1);
    sorted[dst + rank] = pe;
  }
  if (b == 0 && t == 0) roff[N_tot] = E_tot;
}

// ---------------- needed-row flags (layer-3 pruning): batch rows + all knowledge rows ----------------
__global__ __launch_bounds__(256) void k_flag(const int* __restrict__ user_id,
                                              const int* __restrict__ question_id,
                                              int* __restrict__ flags, int B, int NU,
                                              int NUQ, int NC) {
  int i = blockIdx.x * 256 + threadIdx.x;
  if (i < B) {
    flags[user_id[i]] = 1;
    flags[NU + question_id[i]] = 1;
  }
  if (i < NC) flags[NUQ + i] = 1;
}

// ---------------- init: lay0 (bf16) <- emb ----------------
__global__ __launch_bounds__(256) void k_init3(ushort* __restrict__ lay0,
                                               const float* __restrict__ embU,
                                               const float* __restrict__ embE,
                                               const float* __restrict__ embK,
                                               int n4U, int n4E, int n4K) {
  int n4 = n4U + n4E + n4K;
  int stride = gridDim.x * 256;
  ushort4* c4 = (ushort4*)lay0;
  for (int i = blockIdx.x * 256 + threadIdx.x; i < n4; i += stride) {
    const float4* src;
    int j = i;
    if (j < n4U) src = (const float4*)embU;
    else if ((j -= n4U) < n4E) src = (const float4*)embE;
    else { j -= n4E; src = (const float4*)embK; }
    float4 v = src[j];
    ushort4 u;
    u.x = f2bf(v.x); u.y = f2bf(v.y); u.z = f2bf(v.z); u.w = f2bf(v.w);
    c4[i] = u;
  }
}

// ---------------- SpMM core: 4 features/lane, 4 edges in flight per wave (R5-validated) ----------------
__device__ __forceinline__ void spmm_core(const ushort* __restrict__ curb,
                                          const int2* __restrict__ edges,
                                          int beg, int end, int li, int eh,
                                          float& a0, float& a1, float& a2, float& a3) {
  int lane = (eh << 4) | li;
  for (int base = beg; base < end; base += 64) {
    int rem = end - base;
    int m = rem < 64 ? rem : 64;
    int c = 0, vi = 0;
    if (lane < m) {
      int2 pe = edges[base + lane];
      c = pe.x & 0x3FFFFFF;
      vi = pe.y;
    }
    for (int j = 0; j * 4 < m; j += 4) {
      int s0 = (j + 0) * 4 + eh, s1 = (j + 1) * 4 + eh;
      int s2 = (j + 2) * 4 + eh, s3 = (j + 3) * 4 + eh;
      int cc0 = __shfl(c, s0), cc1 = __shfl(c, s1), cc2 = __shfl(c, s2), cc3 = __shfl(c, s3);
      float vf0 = __int_as_float(__shfl(vi, s0));
      float vf1 = __int_as_float(__shfl(vi, s1));
      float vf2 = __int_as_float(__shfl(vi, s2));
      float vf3 = __int_as_float(__shfl(vi, s3));
      uint2 x0 = *(const uint2*)&curb[(size_t)cc0 * 64 + 4 * li];
      uint2 x1 = *(const uint2*)&curb[(size_t)cc1 * 64 + 4 * li];
      uint2 x2 = *(const uint2*)&curb[(size_t)cc2 * 64 + 4 * li];
      uint2 x3 = *(const uint2*)&curb[(size_t)cc3 * 64 + 4 * li];
      a0 = fmaf(vf0, __uint_as_float(x0.x << 16), a0);
      a1 = fmaf(vf0, __uint_as_float(x0.x & 0xffff0000u), a1);
      a2 = fmaf(vf0, __uint_as_float(x0.y << 16), a2);
      a3 = fmaf(vf0, __uint_as_float(x0.y & 0xffff0000u), a3);
      a0 = fmaf(vf1, __uint_as_float(x1.x << 16), a0);
      a1 = fmaf(vf1, __uint_as_float(x1.x & 0xffff0000u), a1);
      a2 = fmaf(vf1, __uint_as_float(x1.y << 16), a2);
      a3 = fmaf(vf1, __uint_as_float(x1.y & 0xffff0000u), a3);
      a0 = fmaf(vf2, __uint_as_float(x2.x << 16), a0);
      a1 = fmaf(vf2, __uint_as_float(x2.x & 0xffff0000u), a1);
      a2 = fmaf(vf2, __uint_as_float(x2.y << 16), a2);
      a3 = fmaf(vf2, __uint_as_float(x2.y & 0xffff0000u), a3);
      a0 = fmaf(vf3, __uint_as_float(x3.x << 16), a0);
      a1 = fmaf(vf3, __uint_as_float(x3.x & 0xffff0000u), a1);
      a2 = fmaf(vf3, __uint_as_float(x3.y << 16), a2);
      a3 = fmaf(vf3, __uint_as_float(x3.y & 0xffff0000u), a3);
    }
  }
  a0 += __shfl_xor(a0, 16); a0 += __shfl_xor(a0, 32);
  a1 += __shfl_xor(a1, 16); a1 += __shfl_xor(a1, 32);
  a2 += __shfl_xor(a2, 16); a2 += __shfl_xor(a2, 32);
  a3 += __shfl_xor(a3, 16); a3 += __shfl_xor(a3, 32);
}

// ---------------- CSR SpMM (row per wave, 8 rows/block): nxt = A@cur + RES*cur ----------------
__global__ __launch_bounds__(512) void k_spmm2(const ushort* __restrict__ curb,
                                               ushort* __restrict__ nxtb,
                                               const int* __restrict__ off,
                                               const int2* __restrict__ edges, int n) {
  int r = blockIdx.x * 8 + (threadIdx.x >> 6);
  if (r >= n) return;
  int lane = threadIdx.x & 63;
  int li = lane & 15, eh = lane >> 4;
  int beg = off[r], end = off[r + 1];
  float a0 = 0.f, a1 = 0.f, a2 = 0.f, a3 = 0.f;
  spmm_core(curb, edges, beg, end, li, eh, a0, a1, a2, a3);
  if (eh == 0) {
    size_t gi = (size_t)r * 64 + 4 * li;
    uint2 cv = *(const uint2*)&curb[gi];
    a0 = fmaf(RESF, __uint_as_float(cv.x << 16), a0);
    a1 = fmaf(RESF, __uint_as_float(cv.x & 0xffff0000u), a1);
    a2 = fmaf(RESF, __uint_as_float(cv.y << 16), a2);
    a3 = fmaf(RESF, __uint_as_float(cv.y & 0xffff0000u), a3);
    uint2 o;
    o.x = ((unsigned)f2bf(a1) << 16) | f2bf(a0);
    o.y = ((unsigned)f2bf(a3) << 16) | f2bf(a2);
    *(uint2*)&nxtb[gi] = o;
  }
}

// ---------------- layer-3 SpMM, flags-direct, fused final accumulate ----------------
// acc[row] = emb[row] + lay1[row] + lay2[row] + (A@lay2 + RES*lay2)[row], flagged rows only
__global__ __launch_bounds__(512) void k_spmm3(const ushort* __restrict__ curb,  // lay2
                                               const ushort* __restrict__ lay1,
                                               const float* __restrict__ embU,
                                               const float* __restrict__ embE,
                                               const float* __restrict__ embK,
                                               float* __restrict__ acc,
                                               const int* __restrict__ off,
                                               const int2* __restrict__ edges,
                                               const int* __restrict__ flags,
                                               int NU, int NQ, int n) {
  int r = blockIdx.x * 8 + (threadIdx.x >> 6);
  if (r >= n) return;
  if (!flags[r]) return;
  int lane = threadIdx.x & 63;
  int li = lane & 15, eh = lane >> 4;
  int beg = off[r], end = off[r + 1];
  float a0 = 0.f, a1 = 0.f, a2 = 0.f, a3 = 0.f;
  spmm_core(curb, edges, beg, end, li, eh, a0, a1, a2, a3);
  if (eh == 0) {
    size_t gi = (size_t)r * 64 + 4 * li;
    const float* ep;
    if (r < NU) ep = embU + gi;
    else if (r < NU + NQ) ep = embE + (gi - (size_t)NU * 64);
    else ep = embK + (gi - (size_t)(NU + NQ) * 64);
    float4 e = *(const float4*)ep;
    uint2 l1 = *(const uint2*)&lay1[gi];
    uint2 c2 = *(const uint2*)&curb[gi];
    float c20 = __uint_as_float(c2.x << 16);
    float c21 = __uint_as_float(c2.x & 0xffff0000u);
    float c22 = __uint_as_float(c2.y << 16);
    float c23 = __uint_as_float(c2.y & 0xffff0000u);
    float4 o;
    o.x = e.x + __uint_as_float(l1.x << 16) + c20 + fmaf(RESF, c20, a0);
    o.y = e.y + __uint_as_float(l1.x & 0xffff0000u) + c21 + fmaf(RESF, c21, a1);
    o.z = e.z + __uint_as_float(l1.y << 16) + c22 + fmaf(RESF, c22, a2);
    o.w = e.w + __uint_as_float(l1.y & 0xffff0000u) + c23 + fmaf(RESF, c23, a3);
    *(float4*)&acc[gi] = o;
  }
}

// ---------------- fused weight prep: kf + W1t/W2t/W3t transposes ----------------
__global__ __launch_bounds__(256) void k_prep(const float* __restrict__ acc_k,
                                              const float* __restrict__ W_k, const float* __restrict__ b_k,
                                              __hip_bfloat16* __restrict__ kfb,
                                              const float* __restrict__ M1_w, __hip_bfloat16* __restrict__ W1t,
                                              const float* __restrict__ M2_w, __hip_bfloat16* __restrict__ W2t,
                                              const float* __restrict__ M3_w, __hip_bfloat16* __restrict__ W3t) {
  int idx = blockIdx.x * 256 + threadIdx.x;
  if (idx < 65536) {
    int d = idx & 127, c = idx >> 7;
    float a = b_k[d];
#pragma unroll 8
    for (int k = 0; k < 64; ++k) a += 0.25f * acc_k[c * 64 + k] * W_k[k * 128 + d];
    float v = a > 0.f ? a : LEAKYF * a;
    kfb[c * 128 + d] = __float2bfloat16(v);
    return;
  }
  int j = idx - 65536;
  if (j < 262144) {  // M1: 512x512
    int n = j >> 9, k = j & 511;
    W1t[n * 512 + k] = __float2bfloat16(M1_w[k * 512 + n]);
    return;
  }
  j -= 262144;
  if (j < 131072) {  // M2: K=512, N=256
    int n = j >> 9, k = j & 511;
    W2t[n * 512 + k] = __float2bfloat16(M2_w[k * 256 + n]);
    return;
  }
  j -= 131072;
  if (j < 32768) {  // M3: K=256, N=128
    int n = j >> 8, k = j & 255;
    W3t[n * 256 + k] = __float2bfloat16(M3_w[k * 128 + n]);
  }
}

// ================= MLP phase =================
__global__ __launch_bounds__(256) void k_diff(
    const int* __restrict__ user_id, const int* __restrict__ question_id,
    const float* __restrict__ acc_u, const float* __restrict__ acc_e,
    const float* __restrict__ W_s, const float* __restrict__ b_s,
    const float* __restrict__ W_e, const float* __restrict__ b_e,
    const float* __restrict__ W_d, const float* __restrict__ b_d,
    __hip_bfloat16* __restrict__ diff, float* __restrict__ disc, int B) {
  __shared__ float bs_l[16 * 64];
  __shared__ float be_l[16 * 64];
  int t = threadIdx.x;
  int row0 = blockIdx.x * 16;
  for (int i = t; i < 16 * 64; i += 256) {
    int r = i >> 6, d = i & 63;
    int gb = row0 + r;
    bs_l[i] = 0.25f * acc_u[(size_t)user_id[gb] * 64 + d];
    be_l[i] = 0.25f * acc_e[(size_t)question_id[gb] * 64 + d];
  }
  __syncthreads();

  int j = t & 127, half = t >> 7;
  float as[8], ae[8];
#pragma unroll
  for (int rr = 0; rr < 8; ++rr) { as[rr] = b_s[j]; ae[rr] = b_e[j]; }
#pragma unroll 4
  for (int k = 0; k < 64; ++k) {
    float ws = W_s[k * 128 + j];
    float we = W_e[k * 128 + j];
#pragma unroll
    for (int rr = 0; rr < 8; ++rr) {
      as[rr] = fmaf(bs_l[(half * 8 + rr) * 64 + k], ws, as[rr]);
      ae[rr] = fmaf(be_l[(half * 8 + rr) * 64 + k], we, ae[rr]);
    }
  }
#pragma unroll
  for (int rr = 0; rr < 8; ++rr) {
    float sfv = as[rr] > 0.f ? as[rr] : LEAKYF * as[rr];
    float efv = ae[rr] > 0.f ? ae[rr] : LEAKYF * ae[rr];
    diff[(size_t)(row0 + half * 8 + rr) * 128 + j] = __float2bfloat16(sfv - efv);
  }
  if (t < 16) {
    float a = b_d[0];
#pragma unroll 8
    for (int k = 0; k < 64; ++k) a = fmaf(be_l[t * 64 + k], W_d[k], a);
    disc[row0 + t] = sigmoid_fast(a);
  }
}

// MODE 0: C = disc * (A@B^T) * q_table   (state)
// MODE 1: C = tanh(A@B^T + bias)
// MODE 2: fused tail: h3 = tanh(A@B^T + bias); out = sigmoid(h3 @ M4w + M4b)  (no C write)
template <int K, int MODE>
__global__ __launch_bounds__(256) void k_gemm(
    const __hip_bfloat16* __restrict__ A, const __hip_bfloat16* __restrict__ Bw,
    __hip_bfloat16* __restrict__ C, int N,
    const float* __restrict__ bias,
    const float* __restrict__ disc, const int* __restrict__ qid,
    const float* __restrict__ q_table,
    const float* __restrict__ M4w, const float* __restrict__ M4b,
    float* __restrict__ outp) {
  __shared__ __align__(16) short lA[128 * 32];
  __shared__ __align__(16) short lB[128 * 32];
  __shared__ float s_disc[128];
  __shared__ int s_qid[128];
  __shared__ float s_bias[128];
  __shared__ float sM4[128];
  __shared__ float spart[128][2];

  int t = threadIdx.x;
  int lane = t & 63;
  int w = t >> 6;
  int wr = (w >> 1) * 64, wc = (w & 1) * 64;
  int bm0 = blockIdx.y * 128, bn0 = blockIdx.x * 128;

  if (MODE == 0) {
    if (t < 128) {
      s_disc[t] = disc[bm0 + t];
      s_qid[t] = qid[bm0 + t];
    }
  } else {
    if (t < 128) s_bias[t] = bias[bn0 + t];
    if (MODE == 2 && t < 128) sM4[t] = M4w[t];
  }

  int off0 = t, off1 = 256 + t;
  int rA0 = off0 >> 2, gq0 = (off0 & 3) ^ ((rA0 >> 1) & 3);
  int rA1 = off1 >> 2, gq1 = (off1 & 3) ^ ((rA1 >> 1) & 3);

  const __hip_bfloat16* Ab = A + (size_t)bm0 * K;
  const __hip_bfloat16* Bb = Bw + (size_t)bn0 * K;

  f32x4 acc[4][4] = {};
  int q = lane >> 4, fr = lane & 15;

  for (int k0 = 0; k0 < K; k0 += 32) {
    __syncthreads();
    gload16(Ab + (size_t)rA0 * K + k0 + gq0 * 8, lA + (size_t)off0 * 8);
    gload16(Ab + (size_t)rA1 * K + k0 + gq1 * 8, lA + (size_t)off1 * 8);
    gload16(Bb + (size_t)rA0 * K + k0 + gq0 * 8, lB + (size_t)off0 * 8);
    gload16(Bb + (size_t)rA1 * K + k0 + gq1 * 8, lB + (size_t)off1 * 8);
    __syncthreads();

    bs8 af[4], bf[4];
#pragma unroll
    for (int mi = 0; mi < 4; ++mi) {
      int row = wr + mi * 16 + fr;
      int a16 = row * 4 + (q ^ ((row >> 1) & 3));
      af[mi] = *(const bs8*)&lA[a16 * 8];
    }
#pragma unroll
    for (int ni = 0; ni < 4; ++ni) {
      int col = wc + ni * 16 + fr;
      int b16 = col * 4 + (q ^ ((col >> 1) & 3));
      bf[ni] = *(const bs8*)&lB[b16 * 8];
    }
#pragma unroll
    for (int mi = 0; mi < 4; ++mi)
#pragma unroll
      for (int ni = 0; ni < 4; ++ni)
        acc[mi][ni] = __builtin_amdgcn_mfma_f32_16x16x32_bf16(af[mi], bf[ni], acc[mi][ni], 0, 0, 0);
  }

  if (MODE == 2) {
#pragma unroll
    for (int mi = 0; mi < 4; ++mi) {
#pragma unroll
      for (int j = 0; j < 4; ++j) {
        int lr = wr + mi * 16 + q * 4 + j;
        float p = 0.f;
#pragma unroll
        for (int ni = 0; ni < 4; ++ni) {
          int lc = wc + ni * 16 + fr;
          p += tanh_fast(acc[mi][ni][j] + s_bias[lc]) * sM4[lc];
        }
        p += __shfl_xor(p, 1);
        p += __shfl_xor(p, 2);
        p += __shfl_xor(p, 4);
        p += __shfl_xor(p, 8);
        if (fr == 0) spart[lr][w & 1] = p;
      }
    }
    __syncthreads();
    if (t < 128) outp[bm0 + t] = sigmoid_fast(spart[t][0] + spart[t][1] + M4b[0]);
    return;
  }

#pragma unroll
  for (int mi = 0; mi < 4; ++mi) {
    int lr0 = wr + mi * 16 + q * 4;
#pragma unroll
    for (int j = 0; j < 4; ++j) {
      int lr = lr0 + j;
      size_t gr = bm0 + lr;
      float dsc = 0.f;
      size_t qrow = 0;
      if (MODE == 0) {
        dsc = s_disc[lr];
        qrow = (size_t)s_qid[lr] * 512;
      }
#pragma unroll
      for (int ni = 0; ni < 4; ++ni) {
        int lc = wc + ni * 16 + fr;
        int gc = bn0 + lc;
        float v = acc[mi][ni][j];
        if (MODE == 0) {
          v = dsc * v * q_table[qrow + gc];
        } else {
          v = tanh_fast(v + s_bias[lc]);
        }
        C[gr * N + gc] = __float2bfloat16(v);
      }
    }
  }
}

// ---------------- host ----------------
static inline int iminh(int a, int b) { return a < b ? a : b; }
static inline size_t rnd4(size_t x) { return (x + 3) & ~(size_t)3; }

extern "C" void kernel_launch(void* const* d_in, const int* in_sizes, int n_in,
                              void* d_out, int out_size, void* d_ws, size_t ws_size,
                              hipStream_t stream) {
  const int* user_id = (const int*)d_in[0];
  const int* question_id = (const int*)d_in[1];
  const float* q_table = (const float*)d_in[2];
  const int* u_row = (const int*)d_in[3];
  const int* u_col = (const int*)d_in[4];
  const float* u_val = (const float*)d_in[5];
  const int* e_row = (const int*)d_in[6];
  const int* e_col = (const int*)d_in[7];
  const float* e_val = (const float*)d_in[8];
  const int* k_row = (const int*)d_in[9];
  const int* k_col = (const int*)d_in[10];
  const float* k_val = (const float*)d_in[11];
  const float* student_emb = (const float*)d_in[12];
  const float* exercise_emb = (const float*)d_in[13];
  const float* knowledge_emb = (const float*)d_in[14];
  const float* W_s = (const float*)d_in[15];
  const float* b_s = (const float*)d_in[16];
  const float* W_e = (const float*)d_in[17];
  const float* b_e = (const float*)d_in[18];
  const float* W_k = (const float*)d_in[19];
  const float* b_k = (const float*)d_in[20];
  const float* W_d = (const float*)d_in[21];
  const float* b_d = (const float*)d_in[22];
  const float* M1_w = (const float*)d_in[23];
  const float* M1_b = (const float*)d_in[24];
  const float* M2_w = (const float*)d_in[25];
  const float* M2_b = (const float*)d_in[26];
  const float* M3_w = (const float*)d_in[27];
  const float* M3_b = (const float*)d_in[28];
  const float* M4_w = (const float*)d_in[29];
  const float* M4_b = (const float*)d_in[30];

  int B = in_sizes[0];
  int NU = in_sizes[12] / 64;
  int NQ = in_sizes[13] / 64;
  int NC = in_sizes[14] / 64;
  int EU = in_sizes[3];
  int EQ = in_sizes[6];
  int EK = in_sizes[9];
  int N_tot = NU + NQ + NC;
  int E_tot = EU + EQ + EK;
  int nbuck = (N_tot + BWID - 1) >> BWSH;

  // ---- workspace: persistent acc + kfb, then UNION region ----
  float* w = (float*)d_ws;
  float* acc = w; w += rnd4((size_t)N_tot * 64);
  __hip_bfloat16* kfb = (__hip_bfloat16*)w; w += rnd4(512 * 128 / 2);
  float* U = w;

  float* acc_u = acc;
  float* acc_e = acc + (size_t)NU * 64;
  float* acc_k = acc + (size_t)(NU + NQ) * 64;

  // conv-phase layout within U
  float* cw = U;
  ushort* lay0 = (ushort*)cw; cw += rnd4((size_t)N_tot * 32);
  ushort* lay1 = (ushort*)cw; cw += rnd4((size_t)N_tot * 32);
  int2* sorted = (int2*)cw;   cw += rnd4((size_t)E_tot * 2);
  int* gcur = (int*)cw;  cw += rnd4(nbuck);
  int* boff = (int*)cw;  cw += rnd4(nbuck + 1);
  int* roff = (int*)cw;  cw += rnd4(N_tot + 1);
  int* flags = (int*)cw; cw += rnd4(N_tot);
  // alias region: tmp (dead after k_sort) overlaps lay2
  float* alias0 = cw;
  int2* tmp = (int2*)alias0;
  ushort* lay2 = (ushort*)alias0;
  {
    size_t tmp_f = rnd4((size_t)nbuck * BSTRIDE * 2);
    size_t lay_f = rnd4((size_t)N_tot * 32);
    cw += (tmp_f > lay_f ? tmp_f : lay_f);
  }

  // mlp-phase layout within U (overlaps conv layout; conv artifacts dead by then)
  float* mw = U;
  __hip_bfloat16* W1t = (__hip_bfloat16*)mw; mw += rnd4(512 * 512 / 2);
  __hip_bfloat16* W2t = (__hip_bfloat16*)mw; mw += rnd4(256 * 512 / 2);
  __hip_bfloat16* W3t = (__hip_bfloat16*)mw; mw += rnd4(128 * 256 / 2);
  __hip_bfloat16* diff = (__hip_bfloat16*)mw; mw += rnd4((size_t)B * 128 / 2);
  float* disc = mw; mw += rnd4(B);
  __hip_bfloat16* state = (__hip_bfloat16*)mw; mw += rnd4((size_t)B * 512 / 2);
  __hip_bfloat16* h1 = (__hip_bfloat16*)mw;    mw += rnd4((size_t)B * 512 / 2);
  __hip_bfloat16* h2 = state;

  // ---- one-time opt-in for >64KB dynamic LDS on the big k_bin variant ----
  static int big_ok = -1;
  if (big_ok < 0) {
    hipError_t e = hipFuncSetAttribute((const void*)k_bin<10>,
                                       hipFuncAttributeMaxDynamicSharedMemorySize,
                                       160 * 1024);
    big_ok = (e == hipSuccess) ? 1 : 0;
    (void)hipGetLastError();  // clear any sticky error from a failed probe
  }

  // ---- setup + edge build: local bucket-sort bin -> compact scan -> row sort ----
  {
    int metaN = (2 * nbuck + 3) & ~3;
    k_setup<<<(N_tot + 255) / 256, 256, 0, stream>>>(gcur, flags, nbuck, N_tot);
    if (big_ok) {
      const int BINCH = 10240;
      int gsb = (E_tot + BINCH - 1) / BINCH;
      size_t ldsb = (size_t)metaN * 4 + (size_t)BINCH * 8 + (size_t)BINCH * 2;
      k_bin<10><<<gsb, 1024, ldsb, stream>>>(u_row, u_col, u_val, e_row, e_col, e_val,
                                             k_row, k_col, k_val, gcur, tmp,
                                             EU, EQ, EK, NU, NQ, nbuck);
    } else {
      const int BINCH = 5120;
      int gsb = (E_tot + BINCH - 1) / BINCH;
      size_t ldsb = (size_t)metaN * 4 + (size_t)BINCH * 8 + (size_t)BINCH * 2;
      k_bin<5><<<gsb, 1024, ldsb, stream>>>(u_row, u_col, u_val, e_row, e_col, e_val,
                                            k_row, k_col, k_val, gcur, tmp,
                                            EU, EQ, EK, NU, NQ, nbuck);
    }
    k_scan2<<<1, 1024, 0, stream>>>(gcur, boff, nbuck);
    k_sort<<<nbuck, 256, 0, stream>>>(tmp, sorted, gcur, boff, roff, N_tot, E_tot);
  }

  // ---- needed-row flags (batch rows + all knowledge rows) ----
  k_flag<<<(B + 255) / 256, 256, 0, stream>>>(user_id, question_id, flags, B, NU,
                                              NU + NQ, NC);

  // ---- convolution: layers 1-2 full, layer 3 flags-pruned + fused accumulate ----
  {
    int n4 = N_tot * 16;
    int gs = iminh((n4 + 255) / 256, 2048);
    k_init3<<<gs, 256, 0, stream>>>(lay0, student_emb, exercise_emb, knowledge_emb,
                                    NU * 16, NQ * 16, NC * 16);
    k_spmm2<<<(N_tot + 7) / 8, 512, 0, stream>>>(lay0, lay1, roff, sorted, N_tot);
    k_spmm2<<<(N_tot + 7) / 8, 512, 0, stream>>>(lay1, lay2, roff, sorted, N_tot);
    k_spmm3<<<(N_tot + 7) / 8, 512, 0, stream>>>(lay2, lay1, student_emb, exercise_emb,
                                                 knowledge_emb, acc, roff, sorted,
                                                 flags, NU, NQ, N_tot);
  }

  // ---- MLP phase (overwrites U; conv done) ----
  k_prep<<<(65536 + 262144 + 131072 + 32768) / 256, 256, 0, stream>>>(
      acc_k, W_k, b_k, kfb, M1_w, W1t, M2_w, W2t, M3_w, W3t);

  k_diff<<<B / 16, 256, 0, stream>>>(user_id, question_id, acc_u, acc_e,
                                     W_s, b_s, W_e, b_e, W_d, b_d, diff, disc, B);

  k_gemm<128, 0><<<dim3(512 / 128, B / 128), 256, 0, stream>>>(
      diff, kfb, state, 512, nullptr, disc, question_id, q_table, nullptr, nullptr, nullptr);
  k_gemm<512, 1><<<dim3(512 / 128, B / 128), 256, 0, stream>>>(
      state, W1t, h1, 512, M1_b, nullptr, nullptr, nullptr, nullptr, nullptr, nullptr);
  k_gemm<512, 1><<<dim3(256 / 128, B / 128), 256, 0, stream>>>(
      h1, W2t, h2, 256, M2_b, nullptr, nullptr, nullptr, nullptr, nullptr, nullptr);
  k_gemm<256, 2><<<dim3(1, B / 128), 256, 0, stream>>>(
      h2, W3t, nullptr, 128, M3_b, nullptr, nullptr, nullptr, M4_w, M4_b, (float*)d_out);
}

// Round 9
// 217.857 us; speedup vs baseline: 1.1255x; 1.0256x over previous
//
#include <hip/hip_runtime.h>
#include <hip/hip_bf16.h>
#include <math.h>

#define RESF 0.8f
#define LEAKYF 0.8f
#define BWSH 6
#define BWID 64
#define BSTRIDE 2432  // bucket capacity; lambda=2048, +8.5 sigma headroom

typedef __attribute__((ext_vector_type(8))) short bs8;
typedef __attribute__((ext_vector_type(4))) float f32x4;

__device__ __forceinline__ void gload16(const void* g, void* l) {
  __builtin_amdgcn_global_load_lds((const __attribute__((address_space(1))) void*)g,
                                   (__attribute__((address_space(3))) void*)l, 16, 0, 0);
}

__device__ __forceinline__ float tanh_fast(float x) {
  float t = __expf(2.f * x);
  return 1.f - 2.f * __builtin_amdgcn_rcpf(1.f + t);
}
__device__ __forceinline__ float sigmoid_fast(float x) {
  return __builtin_amdgcn_rcpf(1.f + __expf(-x));
}
__device__ __forceinline__ ushort f2bf(float a) {
  __hip_bfloat16 h = __float2bfloat16(a);
  return *(ushort*)&h;
}

__device__ __forceinline__ void edge_full(int e,
    const int* __restrict__ rU, const int* __restrict__ cU, const float* __restrict__ vU,
    const int* __restrict__ rE, const int* __restrict__ cE, const float* __restrict__ vE,
    const int* __restrict__ rK, const int* __restrict__ cK, const float* __restrict__ vK,
    int EU, int EQ, int NU, int NQ, int& grow, int& gcol, float& val) {
  if (e < EU) { grow = rU[e]; gcol = cU[e]; val = vU[e]; return; }
  if ((e -= EU) < EQ) { grow = NU + rE[e]; gcol = NU + cE[e]; val = vE[e]; return; }
  e -= EQ;
  grow = NU + NQ + rK[e]; gcol = NU + NQ + cK[e]; val = vK[e];
}

// ---------------- setup: gcur[b] = b*BSTRIDE, flags = 0 ----------------
__global__ __launch_bounds__(256) void k_setup(int* __restrict__ gcur, int* __restrict__ flags,
                                               int nbuck, int N_tot) {
  int i = blockIdx.x * 256 + threadIdx.x;
  if (i < nbuck) gcur[i] = i * BSTRIDE;
  if (i < N_tot) flags[i] = 0;
}

// ---------------- bin: local bucket-sort per block, coalesced run writes (R1-validated) ----------------
// BINR=edges/thread; BINCH=BINR*1024. BINR=10 needs 108.6KB dyn LDS (>64KB opt-in);
// BINR=5 (60.4KB) is the validated fallback.
template <int BINR>
__global__ __launch_bounds__(1024) void k_bin(
    const int* __restrict__ rU, const int* __restrict__ cU, const float* __restrict__ vU,
    const int* __restrict__ rE, const int* __restrict__ cE, const float* __restrict__ vE,
    const int* __restrict__ rK, const int* __restrict__ cK, const float* __restrict__ vK,
    int* __restrict__ gcur, int2* __restrict__ tmp,
    int EU, int EQ, int EK, int NU, int NQ, int nbuck) {
  const int BINCH = BINR * 1024;
  extern __shared__ int l[];
  int metaN = (2 * nbuck + 3) & ~3;
  int* cnt = l;                           // [nbuck] counts -> exclusive offsets -> cursors
  int* dstb = l + nbuck;                  // [nbuck] gbase - local exclusive offset
  int2* spk = (int2*)(l + metaN);         // [BINCH] staged packed edges
  ushort* sbk = (ushort*)(spk + BINCH);   // [BINCH] staged bucket ids
  __shared__ int wsum[16];

  int t = threadIdx.x;
  int lane = t & 63, wid = t >> 6;
  for (int i = t; i < nbuck; i += 1024) cnt[i] = 0;
  __syncthreads();

  int E = EU + EQ + EK;
  int lo = blockIdx.x * BINCH;
  int hi = lo + BINCH < E ? lo + BINCH : E;
  int m = hi - lo;  // edges staged by this block

  int2 pk[BINR];
  int bk[BINR];
#pragma unroll
  for (int k = 0; k < BINR; ++k) {
    int e = lo + t + k * 1024;
    bk[k] = -1;
    if (e < hi) {
      int grow, gcol;
      float val;
      edge_full(e, rU, cU, vU, rE, cE, vE, rK, cK, vK, EU, EQ, NU, NQ, grow, gcol, val);
      pk[k].x = ((grow & (BWID - 1)) << 26) | gcol;
      pk[k].y = __float_as_int(val);
      int b = grow >> BWSH;
      bk[k] = b;
      atomicAdd(&cnt[b], 1);
    }
  }
  __syncthreads();

  // block-wide exclusive scan over nbuck counts (with carry across 1024-wide windows);
  // simultaneously reserve global space and build dstb.
  int carry = 0;
  for (int base = 0; base < nbuck; base += 1024) {
    int i = base + t;
    int x = (i < nbuck) ? cnt[i] : 0;
    int v = x;
#pragma unroll
    for (int d = 1; d < 64; d <<= 1) {
      int y = __shfl_up(v, d);
      if (lane >= d) v += y;
    }
    if (lane == 63) wsum[wid] = v;
    __syncthreads();
    if (t < 16) {
      int w = wsum[t];
#pragma unroll
      for (int d = 1; d < 16; d <<= 1) {
        int y = __shfl_up(w, d);
        if (t >= d) w += y;
      }
      wsum[t] = w;
    }
    __syncthreads();
    int excl = carry + ((wid > 0) ? wsum[wid - 1] : 0) + v - x;
    if (i < nbuck) {
      int gb = x ? atomicAdd(&gcur[i], x) : 0;
      dstb[i] = gb - excl;
      cnt[i] = excl;  // cursor init for scatter phase
    }
    carry += wsum[15];
    __syncthreads();
  }

  // scatter into LDS staging in bucket-sorted order
#pragma unroll
  for (int k = 0; k < BINR; ++k) {
    if (bk[k] >= 0) {
      int p = atomicAdd(&cnt[bk[k]], 1);
      spk[p] = pk[k];
      sbk[p] = (ushort)bk[k];
    }
  }
  __syncthreads();

  // coalesced copy: runs of same-bucket elements land at consecutive global addresses
  for (int i = t; i < m; i += 1024) {
    int b = sbk[i];
    tmp[dstb[b] + i] = spk[i];
  }
}

// ---------------- fused: compact-offset scan (block 0) + needed-row flags (blocks >0) ----------------
__global__ __launch_bounds__(1024) void k_scanflag(const int* __restrict__ gcur, int* __restrict__ boff,
                                                   int n,
                                                   const int* __restrict__ user_id,
                                                   const int* __restrict__ question_id,
                                                   int* __restrict__ flags, int B, int NU,
                                                   int NUQ, int NC) {
  int tid = threadIdx.x;
  if (blockIdx.x > 0) {
    int i = (blockIdx.x - 1) * 1024 + tid;
    if (i < B) {
      flags[user_id[i]] = 1;
      flags[NU + question_id[i]] = 1;
    }
    if (i < NC) flags[NUQ + i] = 1;
    return;
  }
  __shared__ int s[16];
  int lane = tid & 63, wid = tid >> 6;
  int carry = 0;
  for (int base = 0; base < n; base += 1024) {
    int i = base + tid;
    int x = (i < n) ? (gcur[i] - i * BSTRIDE) : 0;
    int v = x;
#pragma unroll
    for (int d = 1; d < 64; d <<= 1) {
      int t = __shfl_up(v, d);
      if (lane >= d) v += t;
    }
    if (lane == 63) s[wid] = v;
    __syncthreads();
    if (tid < 16) {
      int w = s[tid];
#pragma unroll
      for (int d = 1; d < 16; d <<= 1) {
        int t = __shfl_up(w, d);
        if (tid >= d) w += t;
      }
      s[tid] = w;
    }
    __syncthreads();
    int wofs = (wid > 0) ? s[wid - 1] : 0;
    int total = s[15];
    if (i < n) boff[i] = carry + wofs + v - x;
    carry += total;
    __syncthreads();
  }
  if (tid == 0) boff[n] = carry;
}

// ---------------- sort pass: strided bucket segment -> compact exact CSR + row offsets ----------------
// LDS-staged: read the bucket segment from global ONCE (histogram pass), scatter from LDS.
__global__ __launch_bounds__(256) void k_sort(const int2* __restrict__ tmp, int2* __restrict__ sorted,
                                              const int* __restrict__ gcur, const int* __restrict__ boff,
                                              int* __restrict__ roff, int N_tot, int E_tot) {
  __shared__ int2 sedge[BSTRIDE];  // 19456 B
  __shared__ int cnt[BWID];
  __shared__ int cur[BWID];
  int b = blockIdx.x, t = threadIdx.x;
  int beg = b * BSTRIDE, end = gcur[b];
  int m = end - beg;
  if (m > BSTRIDE) m = BSTRIDE;
  int dst = boff[b];
  if (t < BWID) cnt[t] = 0;
  __syncthreads();
  for (int i = t; i < m; i += 256) {
    int2 pe = tmp[beg + i];
    sedge[i] = pe;
    atomicAdd(&cnt[((unsigned)pe.x) >> 26], 1);
  }
  __syncthreads();
  if (t < BWID) {
    int x = cnt[t];
    int v = x;
#pragma unroll
    for (int d = 1; d < 64; d <<= 1) {
      int y = __shfl_up(v, d);
      if (t >= d) v += y;
    }
    cur[t] = v - x;  // exclusive intra-bucket offset
    int r = (b << BWSH) + t;
    if (r < N_tot) roff[r] = dst + v - x;
  }
  __syncthreads();
  for (int i = t; i < m; i += 256) {
    int2 pe = sedge[i];
    int rl = ((unsigned)pe.x) >> 26;
    int rank = atomicAdd(&cur[rl], 1);
    sorted[dst + rank] = pe;
  }
  if (b == 0 && t == 0) roff[N_tot] = E_tot;
}

// ---------------- init: lay0 (bf16) <- emb ----------------
__global__ __launch_bounds__(256) void k_init3(ushort* __restrict__ lay0,
                                               const float* __restrict__ embU,
                                               const float* __restrict__ embE,
                                               const float* __restrict__ embK,
                                               int n4U, int n4E, int n4K) {
  int n4 = n4U + n4E + n4K;
  int stride = gridDim.x * 256;
  ushort4* c4 = (ushort4*)lay0;
  for (int i = blockIdx.x * 256 + threadIdx.x; i < n4; i += stride) {
    const float4* src;
    int j = i;
    if (j < n4U) src = (const float4*)embU;
    else if ((j -= n4U) < n4E) src = (const float4*)embE;
    else { j -= n4E; src = (const float4*)embK; }
    float4 v = src[j];
    ushort4 u;
    u.x = f2bf(v.x); u.y = f2bf(v.y); u.z = f2bf(v.z); u.w = f2bf(v.w);
    c4[i] = u;
  }
}

// ---------------- SpMM core: 4 features/lane, 4 edges in flight per wave (R5-validated) ----------------
__device__ __forceinline__ void spmm_core(const ushort* __restrict__ curb,
                                          const int2* __restrict__ edges,
                                          int beg, int end, int li, int eh,
                                          float& a0, float& a1, float& a2, float& a3) {
  int lane = (eh << 4) | li;
  for (int base = beg; base < end; base += 64) {
    int rem = end - base;
    int m = rem < 64 ? rem : 64;
    int c = 0, vi = 0;
    if (lane < m) {
      int2 pe = edges[base + lane];
      c = pe.x & 0x3FFFFFF;
      vi = pe.y;
    }
    for (int j = 0; j * 4 < m; j += 4) {
      int s0 = (j + 0) * 4 + eh, s1 = (j + 1) * 4 + eh;
      int s2 = (j + 2) * 4 + eh, s3 = (j + 3) * 4 + eh;
      int cc0 = __shfl(c, s0), cc1 = __shfl(c, s1), cc2 = __shfl(c, s2), cc3 = __shfl(c, s3);
      float vf0 = __int_as_float(__shfl(vi, s0));
      float vf1 = __int_as_float(__shfl(vi, s1));
      float vf2 = __int_as_float(__shfl(vi, s2));
      float vf3 = __int_as_float(__shfl(vi, s3));
      uint2 x0 = *(const uint2*)&curb[(size_t)cc0 * 64 + 4 * li];
      uint2 x1 = *(const uint2*)&curb[(size_t)cc1 * 64 + 4 * li];
      uint2 x2 = *(const uint2*)&curb[(size_t)cc2 * 64 + 4 * li];
      uint2 x3 = *(const uint2*)&curb[(size_t)cc3 * 64 + 4 * li];
      a0 = fmaf(vf0, __uint_as_float(x0.x << 16), a0);
      a1 = fmaf(vf0, __uint_as_float(x0.x & 0xffff0000u), a1);
      a2 = fmaf(vf0, __uint_as_float(x0.y << 16), a2);
      a3 = fmaf(vf0, __uint_as_float(x0.y & 0xffff0000u), a3);
      a0 = fmaf(vf1, __uint_as_float(x1.x << 16), a0);
      a1 = fmaf(vf1, __uint_as_float(x1.x & 0xffff0000u), a1);
      a2 = fmaf(vf1, __uint_as_float(x1.y << 16), a2);
      a3 = fmaf(vf1, __uint_as_float(x1.y & 0xffff0000u), a3);
      a0 = fmaf(vf2, __uint_as_float(x2.x << 16), a0);
      a1 = fmaf(vf2, __uint_as_float(x2.x & 0xffff0000u), a1);
      a2 = fmaf(vf2, __uint_as_float(x2.y << 16), a2);
      a3 = fmaf(vf2, __uint_as_float(x2.y & 0xffff0000u), a3);
      a0 = fmaf(vf3, __uint_as_float(x3.x << 16), a0);
      a1 = fmaf(vf3, __uint_as_float(x3.x & 0xffff0000u), a1);
      a2 = fmaf(vf3, __uint_as_float(x3.y << 16), a2);
      a3 = fmaf(vf3, __uint_as_float(x3.y & 0xffff0000u), a3);
    }
  }
  a0 += __shfl_xor(a0, 16); a0 += __shfl_xor(a0, 32);
  a1 += __shfl_xor(a1, 16); a1 += __shfl_xor(a1, 32);
  a2 += __shfl_xor(a2, 16); a2 += __shfl_xor(a2, 32);
  a3 += __shfl_xor(a3, 16); a3 += __shfl_xor(a3, 32);
}

// ---------------- CSR SpMM (row per wave, bf16): nxt = A@cur + RES*cur ----------------
__global__ __launch_bounds__(256) void k_spmm2(const ushort* __restrict__ curb,
                                               ushort* __restrict__ nxtb,
                                               const int* __restrict__ off,
                                               const int2* __restrict__ edges, int n) {
  int r = blockIdx.x * 4 + (threadIdx.x >> 6);
  if (r >= n) return;
  int lane = threadIdx.x & 63;
  int li = lane & 15, eh = lane >> 4;
  int beg = off[r], end = off[r + 1];
  float a0 = 0.f, a1 = 0.f, a2 = 0.f, a3 = 0.f;
  spmm_core(curb, edges, beg, end, li, eh, a0, a1, a2, a3);
  if (eh == 0) {
    size_t gi = (size_t)r * 64 + 4 * li;
    uint2 cv = *(const uint2*)&curb[gi];
    a0 = fmaf(RESF, __uint_as_float(cv.x << 16), a0);
    a1 = fmaf(RESF, __uint_as_float(cv.x & 0xffff0000u), a1);
    a2 = fmaf(RESF, __uint_as_float(cv.y << 16), a2);
    a3 = fmaf(RESF, __uint_as_float(cv.y & 0xffff0000u), a3);
    uint2 o;
    o.x = ((unsigned)f2bf(a1) << 16) | f2bf(a0);
    o.y = ((unsigned)f2bf(a3) << 16) | f2bf(a2);
    *(uint2*)&nxtb[gi] = o;
  }
}

// ---------------- layer-3 SpMM, flags-direct, fused final accumulate ----------------
// acc[row] = emb[row] + lay1[row] + lay2[row] + (A@lay2 + RES*lay2)[row], flagged rows only
__global__ __launch_bounds__(256) void k_spmm3(const ushort* __restrict__ curb,  // lay2
                                               const ushort* __restrict__ lay1,
                                               const float* __restrict__ embU,
                                               const float* __restrict__ embE,
                                               const float* __restrict__ embK,
                                               float* __restrict__ acc,
                                               const int* __restrict__ off,
                                               const int2* __restrict__ edges,
                                               const int* __restrict__ flags,
                                               int NU, int NQ, int n) {
  int r = blockIdx.x * 4 + (threadIdx.x >> 6);
  if (r >= n) return;
  if (!flags[r]) return;
  int lane = threadIdx.x & 63;
  int li = lane & 15, eh = lane >> 4;
  int beg = off[r], end = off[r + 1];
  float a0 = 0.f, a1 = 0.f, a2 = 0.f, a3 = 0.f;
  spmm_core(curb, edges, beg, end, li, eh, a0, a1, a2, a3);
  if (eh == 0) {
    size_t gi = (size_t)r * 64 + 4 * li;
    const float* ep;
    if (r < NU) ep = embU + gi;
    else if (r < NU + NQ) ep = embE + (gi - (size_t)NU * 64);
    else ep = embK + (gi - (size_t)(NU + NQ) * 64);
    float4 e = *(const float4*)ep;
    uint2 l1 = *(const uint2*)&lay1[gi];
    uint2 c2 = *(const uint2*)&curb[gi];
    float c20 = __uint_as_float(c2.x << 16);
    float c21 = __uint_as_float(c2.x & 0xffff0000u);
    float c22 = __uint_as_float(c2.y << 16);
    float c23 = __uint_as_float(c2.y & 0xffff0000u);
    float4 o;
    o.x = e.x + __uint_as_float(l1.x << 16) + c20 + fmaf(RESF, c20, a0);
    o.y = e.y + __uint_as_float(l1.x & 0xffff0000u) + c21 + fmaf(RESF, c21, a1);
    o.z = e.z + __uint_as_float(l1.y << 16) + c22 + fmaf(RESF, c22, a2);
    o.w = e.w + __uint_as_float(l1.y & 0xffff0000u) + c23 + fmaf(RESF, c23, a3);
    *(float4*)&acc[gi] = o;
  }
}

// ---------------- fused weight prep: kf + W1t/W2t/W3t transposes ----------------
__global__ __launch_bounds__(256) void k_prep(const float* __restrict__ acc_k,
                                              const float* __restrict__ W_k, const float* __restrict__ b_k,
                                              __hip_bfloat16* __restrict__ kfb,
                                              const float* __restrict__ M1_w, __hip_bfloat16* __restrict__ W1t,
                                              const float* __restrict__ M2_w, __hip_bfloat16* __restrict__ W2t,
                                              const float* __restrict__ M3_w, __hip_bfloat16* __restrict__ W3t) {
  int idx = blockIdx.x * 256 + threadIdx.x;
  if (idx < 65536) {
    int d = idx & 127, c = idx >> 7;
    float a = b_k[d];
#pragma unroll 8
    for (int k = 0; k < 64; ++k) a += 0.25f * acc_k[c * 64 + k] * W_k[k * 128 + d];
    float v = a > 0.f ? a : LEAKYF * a;
    kfb[c * 128 + d] = __float2bfloat16(v);
    return;
  }
  int j = idx - 65536;
  if (j < 262144) {  // M1: 512x512
    int n = j >> 9, k = j & 511;
    W1t[n * 512 + k] = __float2bfloat16(M1_w[k * 512 + n]);
    return;
  }
  j -= 262144;
  if (j < 131072) {  // M2: K=512, N=256
    int n = j >> 9, k = j & 511;
    W2t[n * 512 + k] = __float2bfloat16(M2_w[k * 256 + n]);
    return;
  }
  j -= 131072;
  if (j < 32768) {  // M3: K=256, N=128
    int n = j >> 8, k = j & 255;
    W3t[n * 256 + k] = __float2bfloat16(M3_w[k * 128 + n]);
  }
}

// ================= MLP phase =================
__global__ __launch_bounds__(256) void k_diff(
    const int* __restrict__ user_id, const int* __restrict__ question_id,
    const float* __restrict__ acc_u, const float* __restrict__ acc_e,
    const float* __restrict__ W_s, const float* __restrict__ b_s,
    const float* __restrict__ W_e, const float* __restrict__ b_e,
    const float* __restrict__ W_d, const float* __restrict__ b_d,
    __hip_bfloat16* __restrict__ diff, float* __restrict__ disc, int B) {
  __shared__ float bs_l[16 * 64];
  __shared__ float be_l[16 * 64];
  int t = threadIdx.x;
  int row0 = blockIdx.x * 16;
  for (int i = t; i < 16 * 64; i += 256) {
    int r = i >> 6, d = i & 63;
    int gb = row0 + r;
    bs_l[i] = 0.25f * acc_u[(size_t)user_id[gb] * 64 + d];
    be_l[i] = 0.25f * acc_e[(size_t)question_id[gb] * 64 + d];
  }
  __syncthreads();

  int j = t & 127, half = t >> 7;
  float as[8], ae[8];
#pragma unroll
  for (int rr = 0; rr < 8; ++rr) { as[rr] = b_s[j]; ae[rr] = b_e[j]; }
#pragma unroll 4
  for (int k = 0; k < 64; ++k) {
    float ws = W_s[k * 128 + j];
    float we = W_e[k * 128 + j];
#pragma unroll
    for (int rr = 0; rr < 8; ++rr) {
      as[rr] = fmaf(bs_l[(half * 8 + rr) * 64 + k], ws, as[rr]);
      ae[rr] = fmaf(be_l[(half * 8 + rr) * 64 + k], we, ae[rr]);
    }
  }
#pragma unroll
  for (int rr = 0; rr < 8; ++rr) {
    float sfv = as[rr] > 0.f ? as[rr] : LEAKYF * as[rr];
    float efv = ae[rr] > 0.f ? ae[rr] : LEAKYF * ae[rr];
    diff[(size_t)(row0 + half * 8 + rr) * 128 + j] = __float2bfloat16(sfv - efv);
  }
  if (t < 16) {
    float a = b_d[0];
#pragma unroll 8
    for (int k = 0; k < 64; ++k) a = fmaf(be_l[t * 64 + k], W_d[k], a);
    disc[row0 + t] = sigmoid_fast(a);
  }
}

// MODE 0: C = disc * (A@B^T) * q_table   (state)
// MODE 1: C = tanh(A@B^T + bias)
// MODE 2: fused tail: h3 = tanh(A@B^T + bias); out = sigmoid(h3 @ M4w + M4b)  (no C write)
template <int K, int MODE>
__global__ __launch_bounds__(256) void k_gemm(
    const __hip_bfloat16* __restrict__ A, const __hip_bfloat16* __restrict__ Bw,
    __hip_bfloat16* __restrict__ C, int N,
    const float* __restrict__ bias,
    const float* __restrict__ disc, const int* __restrict__ qid,
    const float* __restrict__ q_table,
    const float* __restrict__ M4w, const float* __restrict__ M4b,
    float* __restrict__ outp) {
  __shared__ __align__(16) short lA[128 * 32];
  __shared__ __align__(16) short lB[128 * 32];
  __shared__ float s_disc[128];
  __shared__ int s_qid[128];
  __shared__ float s_bias[128];
  __shared__ float sM4[128];
  __shared__ float spart[128][2];

  int t = threadIdx.x;
  int lane = t & 63;
  int w = t >> 6;
  int wr = (w >> 1) * 64, wc = (w & 1) * 64;
  int bm0 = blockIdx.y * 128, bn0 = blockIdx.x * 128;

  if (MODE == 0) {
    if (t < 128) {
      s_disc[t] = disc[bm0 + t];
      s_qid[t] = qid[bm0 + t];
    }
  } else {
    if (t < 128) s_bias[t] = bias[bn0 + t];
    if (MODE == 2 && t < 128) sM4[t] = M4w[t];
  }

  int off0 = t, off1 = 256 + t;
  int rA0 = off0 >> 2, gq0 = (off0 & 3) ^ ((rA0 >> 1) & 3);
  int rA1 = off1 >> 2, gq1 = (off1 & 3) ^ ((rA1 >> 1) & 3);

  const __hip_bfloat16* Ab = A + (size_t)bm0 * K;
  const __hip_bfloat16* Bb = Bw + (size_t)bn0 * K;

  f32x4 acc[4][4] = {};
  int q = lane >> 4, fr = lane & 15;

  for (int k0 = 0; k0 < K; k0 += 32) {
    __syncthreads();
    gload16(Ab + (size_t)rA0 * K + k0 + gq0 * 8, lA + (size_t)off0 * 8);
    gload16(Ab + (size_t)rA1 * K + k0 + gq1 * 8, lA + (size_t)off1 * 8);
    gload16(Bb + (size_t)rA0 * K + k0 + gq0 * 8, lB + (size_t)off0 * 8);
    gload16(Bb + (size_t)rA1 * K + k0 + gq1 * 8, lB + (size_t)off1 * 8);
    __syncthreads();

    bs8 af[4], bf[4];
#pragma unroll
    for (int mi = 0; mi < 4; ++mi) {
      int row = wr + mi * 16 + fr;
      int a16 = row * 4 + (q ^ ((row >> 1) & 3));
      af[mi] = *(const bs8*)&lA[a16 * 8];
    }
#pragma unroll
    for (int ni = 0; ni < 4; ++ni) {
      int col = wc + ni * 16 + fr;
      int b16 = col * 4 + (q ^ ((col >> 1) & 3));
      bf[ni] = *(const bs8*)&lB[b16 * 8];
    }
#pragma unroll
    for (int mi = 0; mi < 4; ++mi)
#pragma unroll
      for (int ni = 0; ni < 4; ++ni)
        acc[mi][ni] = __builtin_amdgcn_mfma_f32_16x16x32_bf16(af[mi], bf[ni], acc[mi][ni], 0, 0, 0);
  }

  if (MODE == 2) {
#pragma unroll
    for (int mi = 0; mi < 4; ++mi) {
#pragma unroll
      for (int j = 0; j < 4; ++j) {
        int lr = wr + mi * 16 + q * 4 + j;
        float p = 0.f;
#pragma unroll
        for (int ni = 0; ni < 4; ++ni) {
          int lc = wc + ni * 16 + fr;
          p += tanh_fast(acc[mi][ni][j] + s_bias[lc]) * sM4[lc];
        }
        p += __shfl_xor(p, 1);
        p += __shfl_xor(p, 2);
        p += __shfl_xor(p, 4);
        p += __shfl_xor(p, 8);
        if (fr == 0) spart[lr][w & 1] = p;
      }
    }
    __syncthreads();
    if (t < 128) outp[bm0 + t] = sigmoid_fast(spart[t][0] + spart[t][1] + M4b[0]);
    return;
  }

#pragma unroll
  for (int mi = 0; mi < 4; ++mi) {
    int lr0 = wr + mi * 16 + q * 4;
#pragma unroll
    for (int j = 0; j < 4; ++j) {
      int lr = lr0 + j;
      size_t gr = bm0 + lr;
      float dsc = 0.f;
      size_t qrow = 0;
      if (MODE == 0) {
        dsc = s_disc[lr];
        qrow = (size_t)s_qid[lr] * 512;
      }
#pragma unroll
      for (int ni = 0; ni < 4; ++ni) {
        int lc = wc + ni * 16 + fr;
        int gc = bn0 + lc;
        float v = acc[mi][ni][j];
        if (MODE == 0) {
          v = dsc * v * q_table[qrow + gc];
        } else {
          v = tanh_fast(v + s_bias[lc]);
        }
        C[gr * N + gc] = __float2bfloat16(v);
      }
    }
  }
}

// ---------------- host ----------------
static inline int iminh(int a, int b) { return a < b ? a : b; }
static inline size_t rnd4(size_t x) { return (x + 3) & ~(size_t)3; }

extern "C" void kernel_launch(void* const* d_in, const int* in_sizes, int n_in,
                              void* d_out, int out_size, void* d_ws, size_t ws_size,
                              hipStream_t stream) {
  const int* user_id = (const int*)d_in[0];
  const int* question_id = (const int*)d_in[1];
  const float* q_table = (const float*)d_in[2];
  const int* u_row = (const int*)d_in[3];
  const int* u_col = (const int*)d_in[4];
  const float* u_val = (const float*)d_in[5];
  const int* e_row = (const int*)d_in[6];
  const int* e_col = (const int*)d_in[7];
  const float* e_val = (const float*)d_in[8];
  const int* k_row = (const int*)d_in[9];
  const int* k_col = (const int*)d_in[10];
  const float* k_val = (const float*)d_in[11];
  const float* student_emb = (const float*)d_in[12];
  const float* exercise_emb = (const float*)d_in[13];
  const float* knowledge_emb = (const float*)d_in[14];
  const float* W_s = (const float*)d_in[15];
  const float* b_s = (const float*)d_in[16];
  const float* W_e = (const float*)d_in[17];
  const float* b_e = (const float*)d_in[18];
  const float* W_k = (const float*)d_in[19];
  const float* b_k = (const float*)d_in[20];
  const float* W_d = (const float*)d_in[21];
  const float* b_d = (const float*)d_in[22];
  const float* M1_w = (const float*)d_in[23];
  const float* M1_b = (const float*)d_in[24];
  const float* M2_w = (const float*)d_in[25];
  const float* M2_b = (const float*)d_in[26];
  const float* M3_w = (const float*)d_in[27];
  const float* M3_b = (const float*)d_in[28];
  const float* M4_w = (const float*)d_in[29];
  const float* M4_b = (const float*)d_in[30];

  int B = in_sizes[0];
  int NU = in_sizes[12] / 64;
  int NQ = in_sizes[13] / 64;
  int NC = in_sizes[14] / 64;
  int EU = in_sizes[3];
  int EQ = in_sizes[6];
  int EK = in_sizes[9];
  int N_tot = NU + NQ + NC;
  int E_tot = EU + EQ + EK;
  int nbuck = (N_tot + BWID - 1) >> BWSH;

  // ---- workspace: persistent acc + kfb, then UNION region ----
  float* w = (float*)d_ws;
  float* acc = w; w += rnd4((size_t)N_tot * 64);
  __hip_bfloat16* kfb = (__hip_bfloat16*)w; w += rnd4(512 * 128 / 2);
  float* U = w;

  float* acc_u = acc;
  float* acc_e = acc + (size_t)NU * 64;
  float* acc_k = acc + (size_t)(NU + NQ) * 64;

  // conv-phase layout within U
  float* cw = U;
  ushort* lay0 = (ushort*)cw; cw += rnd4((size_t)N_tot * 32);
  ushort* lay1 = (ushort*)cw; cw += rnd4((size_t)N_tot * 32);
  int2* sorted = (int2*)cw;   cw += rnd4((size_t)E_tot * 2);
  int* gcur = (int*)cw;  cw += rnd4(nbuck);
  int* boff = (int*)cw;  cw += rnd4(nbuck + 1);
  int* roff = (int*)cw;  cw += rnd4(N_tot + 1);
  int* flags = (int*)cw; cw += rnd4(N_tot);
  // alias region: tmp (dead after k_sort) overlaps lay2
  float* alias0 = cw;
  int2* tmp = (int2*)alias0;
  ushort* lay2 = (ushort*)alias0;
  {
    size_t tmp_f = rnd4((size_t)nbuck * BSTRIDE * 2);
    size_t lay_f = rnd4((size_t)N_tot * 32);
    cw += (tmp_f > lay_f ? tmp_f : lay_f);
  }

  // mlp-phase layout within U (overlaps conv layout; conv artifacts dead by then)
  float* mw = U;
  __hip_bfloat16* W1t = (__hip_bfloat16*)mw; mw += rnd4(512 * 512 / 2);
  __hip_bfloat16* W2t = (__hip_bfloat16*)mw; mw += rnd4(256 * 512 / 2);
  __hip_bfloat16* W3t = (__hip_bfloat16*)mw; mw += rnd4(128 * 256 / 2);
  __hip_bfloat16* diff = (__hip_bfloat16*)mw; mw += rnd4((size_t)B * 128 / 2);
  float* disc = mw; mw += rnd4(B);
  __hip_bfloat16* state = (__hip_bfloat16*)mw; mw += rnd4((size_t)B * 512 / 2);
  __hip_bfloat16* h1 = (__hip_bfloat16*)mw;    mw += rnd4((size_t)B * 512 / 2);
  __hip_bfloat16* h2 = state;

  // ---- one-time opt-in for >64KB dynamic LDS on the big k_bin variant ----
  static int big_ok = -1;
  if (big_ok < 0) {
    hipError_t e = hipFuncSetAttribute((const void*)k_bin<10>,
                                       hipFuncAttributeMaxDynamicSharedMemorySize,
                                       160 * 1024);
    big_ok = (e == hipSuccess) ? 1 : 0;
    (void)hipGetLastError();  // clear any sticky error from a failed probe
  }

  // ---- setup + edge build: local bucket-sort bin -> compact scan(+flags) -> row sort ----
  {
    int metaN = (2 * nbuck + 3) & ~3;
    k_setup<<<(N_tot + 255) / 256, 256, 0, stream>>>(gcur, flags, nbuck, N_tot);
    if (big_ok) {
      const int BINCH = 10240;
      int gsb = (E_tot + BINCH - 1) / BINCH;
      size_t ldsb = (size_t)metaN * 4 + (size_t)BINCH * 8 + (size_t)BINCH * 2;
      k_bin<10><<<gsb, 1024, ldsb, stream>>>(u_row, u_col, u_val, e_row, e_col, e_val,
                                             k_row, k_col, k_val, gcur, tmp,
                                             EU, EQ, EK, NU, NQ, nbuck);
    } else {
      const int BINCH = 5120;
      int gsb = (E_tot + BINCH - 1) / BINCH;
      size_t ldsb = (size_t)metaN * 4 + (size_t)BINCH * 8 + (size_t)BINCH * 2;
      k_bin<5><<<gsb, 1024, ldsb, stream>>>(u_row, u_col, u_val, e_row, e_col, e_val,
                                            k_row, k_col, k_val, gcur, tmp,
                                            EU, EQ, EK, NU, NQ, nbuck);
    }
    int fb = (B + 1023) / 1024;  // flag blocks (B >= NC)
    k_scanflag<<<1 + fb, 1024, 0, stream>>>(gcur, boff, nbuck,
                                            user_id, question_id, flags, B, NU,
                                            NU + NQ, NC);
    k_sort<<<nbuck, 256, 0, stream>>>(tmp, sorted, gcur, boff, roff, N_tot, E_tot);
  }

  // ---- convolution: layers 1-2 full, layer 3 flags-pruned + fused accumulate ----
  {
    int n4 = N_tot * 16;
    int gs = iminh((n4 + 255) / 256, 2048);
    k_init3<<<gs, 256, 0, stream>>>(lay0, student_emb, exercise_emb, knowledge_emb,
                                    NU * 16, NQ * 16, NC * 16);
    k_spmm2<<<(N_tot + 3) / 4, 256, 0, stream>>>(lay0, lay1, roff, sorted, N_tot);
    k_spmm2<<<(N_tot + 3) / 4, 256, 0, stream>>>(lay1, lay2, roff, sorted, N_tot);
    k_spmm3<<<(N_tot + 3) / 4, 256, 0, stream>>>(lay2, lay1, student_emb, exercise_emb,
                                                 knowledge_emb, acc, roff, sorted,
                                                 flags, NU, NQ, N_tot);
  }

  // ---- MLP phase (overwrites U; conv done) ----
  k_prep<<<(65536 + 262144 + 131072 + 32768) / 256, 256, 0, stream>>>(
      acc_k, W_k, b_k, kfb, M1_w, W1t, M2_w, W2t, M3_w, W3t);

  k_diff<<<B / 16, 256, 0, stream>>>(user_id, question_id, acc_u, acc_e,
                                     W_s, b_s, W_e, b_e, W_d, b_d, diff, disc, B);

  k_gemm<128, 0><<<dim3(512 / 128, B / 128), 256, 0, stream>>>(
      diff, kfb, state, 512, nullptr, disc, question_id, q_table, nullptr, nullptr, nullptr);
  k_gemm<512, 1><<<dim3(512 / 128, B / 128), 256, 0, stream>>>(
      state, W1t, h1, 512, M1_b, nullptr, nullptr, nullptr, nullptr, nullptr, nullptr);
  k_gemm<512, 1><<<dim3(256 / 128, B / 128), 256, 0, stream>>>(
      h1, W2t, h2, 256, M2_b, nullptr, nullptr, nullptr, nullptr, nullptr, nullptr);
  k_gemm<256, 2><<<dim3(1, B / 128), 256, 0, stream>>>(
      h2, W3t, nullptr, 128, M3_b, nullptr, nullptr, nullptr, M4_w, M4_b, (float*)d_out);
}